// Round 11
// baseline (443.886 us; speedup 1.0000x reference)
//
#include <hip/hip_runtime.h>
#include <hip/hip_fp16.h>
#include <cmath>

typedef unsigned short ushort_t;
typedef unsigned int uint_t;

#define N_TOT 30000
#define N0_   18000
#define R_    5
#define E_    600000
#define RN    (R_ * N_TOT)
#define NC_   (N_TOT * 8)        // logits elements
#define NX_   (N_TOT * 128)      // x elements
#define NL_   (N_TOT * 64)      // node*lane pairs
#define SCAN_NB ((RN + 1023) / 1024)   // 147 blocks of 1024 elements

typedef __attribute__((ext_vector_type(8))) short bf16x8;
typedef __attribute__((ext_vector_type(4))) float f32x4;
typedef __attribute__((ext_vector_type(2))) float f32x2;
typedef __attribute__((ext_vector_type(4))) int int4v;

__device__ __forceinline__ ushort_t f2bf(float f) {
    uint_t u = __float_as_uint(f);
    uint_t r = (u + 0x7fffu + ((u >> 16) & 1u)) >> 16;   // RTNE
    return (ushort_t)r;
}
__device__ __forceinline__ float bflo(uint_t v) { return __uint_as_float(v << 16); }
__device__ __forceinline__ float bfhi(uint_t v) { return __uint_as_float(v & 0xffff0000u); }

// ---------------------------------------------------------------------------
// init: u = 1/R, act[0]=1, act[1..15]=0
// ---------------------------------------------------------------------------
__global__ void init_kernel(float* ug, int* act) {
    if (threadIdx.x < 16) act[threadIdx.x] = (threadIdx.x == 0) ? 1 : 0;
    if (threadIdx.x < 5) ug[threadIdx.x] = 0.2f;
}

// ---------------------------------------------------------------------------
// bf16 pre-conversion: feats row-major, weights transposed [col][k]
// ---------------------------------------------------------------------------
__global__ __launch_bounds__(256) void cvtfeat_kernel(const float* __restrict__ in,
                                                      ushort_t* __restrict__ out,
                                                      int nelem)
{
    int i = (blockIdx.x * 256 + threadIdx.x) * 4;
    if (i >= nelem) return;
    const float4 v = *(const float4*)(in + i);
    ushort_t o0 = f2bf(v.x), o1 = f2bf(v.y), o2 = f2bf(v.z), o3 = f2bf(v.w);
    uint_t p0 = (uint_t)o0 | ((uint_t)o1 << 16);
    uint_t p1 = (uint_t)o2 | ((uint_t)o3 << 16);
    uint2* op = (uint2*)(out + i);
    *op = make_uint2(p0, p1);
}

__global__ __launch_bounds__(256) void cvtw_kernel(const float* __restrict__ W,
                                                   ushort_t* __restrict__ wt, int K)
{
    int idx = blockIdx.x * 256 + threadIdx.x;   // idx = j*K + k
    if (idx >= 128 * K) return;
    int j = idx / K, k = idx - j * K;
    wt[idx] = f2bf(W[k * 128 + j]);
}

// ---------------------------------------------------------------------------
// MFMA MLP: 32 nodes per 256-thread block (4 waves) — unchanged.
// ---------------------------------------------------------------------------
__global__ __launch_bounds__(256) void mlp_mfma_kernel(
    const ushort_t* __restrict__ fb0, const ushort_t* __restrict__ fb1,
    const ushort_t* __restrict__ wt0, const ushort_t* __restrict__ wt1,
    const ushort_t* __restrict__ wtm1, const ushort_t* __restrict__ wtm2,
    const float* __restrict__ b0, const float* __restrict__ b1,
    const float* __restrict__ bm1, const float* __restrict__ bm2,
    float* __restrict__ xout, ushort_t* __restrict__ xh)
{
    const int t = threadIdx.x;
    const int lane = t & 63;
    const int wv = t >> 6;            // 0..3 -> col block wv*32
    const int lr = lane & 15;         // A-row / B-col within tile
    const int lg = lane >> 4;         // k-group, D row-group
    const int row0 = blockIdx.x * 32;

    __shared__ ushort_t hls[32][136];   // bf16 h   (pad: 272B row stride)
    __shared__ float    tls[32][132];   // fp32 t1/t2 (pad: 528B row stride)
    __shared__ ushort_t zls[32][136];   // bf16 z

    // ---------------- GEMM1: h = feat @ W + b -------------------------------
    #pragma unroll
    for (int mt = 0; mt < 2; ++mt) {
        const int rb = row0 + mt * 16;
        const bool is0 = (rb < N0_);
        const int r = min(rb + lr, N_TOT - 1);
        const ushort_t* __restrict__ fa =
            is0 ? fb0 + (size_t)r * 256 : fb1 + (size_t)(r - N0_) * 128;
        const ushort_t* __restrict__ wt = is0 ? wt0 : wt1;
        const int K = is0 ? 256 : 128;
        const int c0 = wv * 32 + lr;

        f32x4 a0 = {0.f, 0.f, 0.f, 0.f};
        f32x4 a1 = {0.f, 0.f, 0.f, 0.f};
        for (int ks = 0; ks < K; ks += 32) {
            const bf16x8 af = *(const bf16x8*)(fa + ks + lg * 8);
            const bf16x8 wb0 = *(const bf16x8*)(wt + (size_t)c0 * K + ks + lg * 8);
            const bf16x8 wb1 = *(const bf16x8*)(wt + (size_t)(c0 + 16) * K + ks + lg * 8);
            a0 = __builtin_amdgcn_mfma_f32_16x16x32_bf16(af, wb0, a0, 0, 0, 0);
            a1 = __builtin_amdgcn_mfma_f32_16x16x32_bf16(af, wb1, a1, 0, 0, 0);
        }
        const float bb0 = is0 ? b0[c0] : b1[c0];
        const float bb1 = is0 ? b0[c0 + 16] : b1[c0 + 16];
        #pragma unroll
        for (int j = 0; j < 4; ++j) {
            hls[mt * 16 + lg * 4 + j][c0]      = f2bf(a0[j] + bb0);
            hls[mt * 16 + lg * 4 + j][c0 + 16] = f2bf(a1[j] + bb1);
        }
    }
    __syncthreads();

    // ---------------- GEMM2: t1 = h @ Wm1 + bm1 -----------------------------
    {
        const int c0 = wv * 32 + lr;
        f32x4 g00 = {0.f,0.f,0.f,0.f}, g01 = {0.f,0.f,0.f,0.f};
        f32x4 g10 = {0.f,0.f,0.f,0.f}, g11 = {0.f,0.f,0.f,0.f};
        for (int ks = 0; ks < 128; ks += 32) {
            const bf16x8 wb0 = *(const bf16x8*)(wtm1 + (size_t)c0 * 128 + ks + lg * 8);
            const bf16x8 wb1 = *(const bf16x8*)(wtm1 + (size_t)(c0 + 16) * 128 + ks + lg * 8);
            const bf16x8 af0 = *(const bf16x8*)(&hls[lr][ks + lg * 8]);
            const bf16x8 af1 = *(const bf16x8*)(&hls[16 + lr][ks + lg * 8]);
            g00 = __builtin_amdgcn_mfma_f32_16x16x32_bf16(af0, wb0, g00, 0, 0, 0);
            g01 = __builtin_amdgcn_mfma_f32_16x16x32_bf16(af0, wb1, g01, 0, 0, 0);
            g10 = __builtin_amdgcn_mfma_f32_16x16x32_bf16(af1, wb0, g10, 0, 0, 0);
            g11 = __builtin_amdgcn_mfma_f32_16x16x32_bf16(af1, wb1, g11, 0, 0, 0);
        }
        const float bb0 = bm1[c0], bb1 = bm1[c0 + 16];
        #pragma unroll
        for (int j = 0; j < 4; ++j) {
            tls[lg * 4 + j][c0]           = g00[j] + bb0;
            tls[lg * 4 + j][c0 + 16]      = g01[j] + bb1;
            tls[16 + lg * 4 + j][c0]      = g10[j] + bb0;
            tls[16 + lg * 4 + j][c0 + 16] = g11[j] + bb1;
        }
    }
    __syncthreads();

    // ---------------- LN + relu -> z (bf16) ---------------------------------
    {
        const int row = t >> 3, seg = t & 7;
        f32x4 v[4];
        float s = 0.f;
        #pragma unroll
        for (int i = 0; i < 4; ++i) {
            v[i] = *(const f32x4*)(&tls[row][seg * 16 + i * 4]);
            s += v[i][0] + v[i][1] + v[i][2] + v[i][3];
        }
        #pragma unroll
        for (int o = 1; o < 8; o <<= 1) s += __shfl_xor(s, o, 64);
        const float mean = s * (1.0f / 128.0f);
        float q = 0.f;
        #pragma unroll
        for (int i = 0; i < 4; ++i) {
            #pragma unroll
            for (int e = 0; e < 4; ++e) { float d = v[i][e] - mean; q = fmaf(d, d, q); }
        }
        #pragma unroll
        for (int o = 1; o < 8; o <<= 1) q += __shfl_xor(q, o, 64);
        const float inv = 1.0f / sqrtf(q * (1.0f / 128.0f) + 1e-5f);
        uint_t* zp = (uint_t*)&zls[row][0];
        #pragma unroll
        for (int i = 0; i < 4; ++i) {
            ushort_t z0 = f2bf(fmaxf((v[i][0] - mean) * inv, 0.0f));
            ushort_t z1 = f2bf(fmaxf((v[i][1] - mean) * inv, 0.0f));
            ushort_t z2 = f2bf(fmaxf((v[i][2] - mean) * inv, 0.0f));
            ushort_t z3 = f2bf(fmaxf((v[i][3] - mean) * inv, 0.0f));
            zp[(seg * 16 + i * 4) / 2]     = (uint_t)z0 | ((uint_t)z1 << 16);
            zp[(seg * 16 + i * 4) / 2 + 1] = (uint_t)z2 | ((uint_t)z3 << 16);
        }
    }
    __syncthreads();

    // ---------------- GEMM3: t2 = z @ Wm2 + bm2 -----------------------------
    {
        const int c0 = wv * 32 + lr;
        f32x4 g00 = {0.f,0.f,0.f,0.f}, g01 = {0.f,0.f,0.f,0.f};
        f32x4 g10 = {0.f,0.f,0.f,0.f}, g11 = {0.f,0.f,0.f,0.f};
        for (int ks = 0; ks < 128; ks += 32) {
            const bf16x8 wb0 = *(const bf16x8*)(wtm2 + (size_t)c0 * 128 + ks + lg * 8);
            const bf16x8 wb1 = *(const bf16x8*)(wtm2 + (size_t)(c0 + 16) * 128 + ks + lg * 8);
            const bf16x8 af0 = *(const bf16x8*)(&zls[lr][ks + lg * 8]);
            const bf16x8 af1 = *(const bf16x8*)(&zls[16 + lr][ks + lg * 8]);
            g00 = __builtin_amdgcn_mfma_f32_16x16x32_bf16(af0, wb0, g00, 0, 0, 0);
            g01 = __builtin_amdgcn_mfma_f32_16x16x32_bf16(af0, wb1, g01, 0, 0, 0);
            g10 = __builtin_amdgcn_mfma_f32_16x16x32_bf16(af1, wb0, g10, 0, 0, 0);
            g11 = __builtin_amdgcn_mfma_f32_16x16x32_bf16(af1, wb1, g11, 0, 0, 0);
        }
        __syncthreads();   // all zls reads done before tls is overwritten below
        const float bb0 = bm2[c0], bb1 = bm2[c0 + 16];
        #pragma unroll
        for (int j = 0; j < 4; ++j) {
            tls[lg * 4 + j][c0]           = g00[j] + bb0;
            tls[lg * 4 + j][c0 + 16]      = g01[j] + bb1;
            tls[16 + lg * 4 + j][c0]      = g10[j] + bb0;
            tls[16 + lg * 4 + j][c0 + 16] = g11[j] + bb1;
        }
    }
    __syncthreads();

    // ---------------- per-row standardization + store -----------------------
    {
        const int row = t >> 3, seg = t & 7;
        const int n = row0 + row;
        f32x4 v[4];
        float s = 0.f;
        #pragma unroll
        for (int i = 0; i < 4; ++i) {
            v[i] = *(const f32x4*)(&tls[row][seg * 16 + i * 4]);
            s += v[i][0] + v[i][1] + v[i][2] + v[i][3];
        }
        #pragma unroll
        for (int o = 1; o < 8; o <<= 1) s += __shfl_xor(s, o, 64);
        const float mu = s * (1.0f / 128.0f);
        float q = 0.f;
        #pragma unroll
        for (int i = 0; i < 4; ++i) {
            #pragma unroll
            for (int e = 0; e < 4; ++e) { float d = v[i][e] - mu; q = fmaf(d, d, q); }
        }
        #pragma unroll
        for (int o = 1; o < 8; o <<= 1) q += __shfl_xor(q, o, 64);
        const float sd = sqrtf(q * (1.0f / 127.0f));
        const float inv = 1.0f / sd;
        if (n < N_TOT) {
            uint_t* xhp = (uint_t*)xh + (size_t)n * 64 + seg * 8;
            float* xop = xout + (size_t)n * 128 + seg * 16;
            #pragma unroll
            for (int i = 0; i < 4; ++i) {
                float rr[4];
                #pragma unroll
                for (int e = 0; e < 4; ++e) {
                    float r = (v[i][e] - mu) * inv;
                    if (!(fabsf(r) <= 3.402823466e38f)) {
                        r = (r != r) ? 0.0f : ((r > 0.0f) ? 3.402823466e38f : -3.402823466e38f);
                    }
                    rr[e] = r;
                }
                *(float4*)(xop + i * 4) = make_float4(rr[0], rr[1], rr[2], rr[3]);
                xhp[i * 2]     = (uint_t)f2bf(rr[0]) | ((uint_t)f2bf(rr[1]) << 16);
                xhp[i * 2 + 1] = (uint_t)f2bf(rr[2]) | ((uint_t)f2bf(rr[3]) << 16);
            }
        }
    }
}

// ---------------------------------------------------------------------------
// preprocessing — node-major keys: key = src*5 + rel
// ---------------------------------------------------------------------------
__global__ void deg_kernel(const int* __restrict__ src, const int* __restrict__ rel,
                           int* __restrict__ deg_i)
{
    int e = blockIdx.x * 256 + threadIdx.x;
    if (e >= E_) return;
    atomicAdd(&deg_i[src[e] * R_ + rel[e]], 1);
}

__global__ void dinv_kernel(const int* __restrict__ deg_i, float* __restrict__ dinv)
{
    int i = blockIdx.x * 256 + threadIdx.x;
    if (i >= RN) return;
    int dg = deg_i[i];
    dinv[i] = (dg > 0) ? 1.0f / sqrtf((float)dg) : 0.0f;
}

// 3-pass parallel exclusive scan over RN elements
__global__ __launch_bounds__(256) void scan1_kernel(const int* __restrict__ cnt,
                                                    int* __restrict__ rp,
                                                    int* __restrict__ bsum)
{
    __shared__ int wsum[4];
    const int t = threadIdx.x, lane = t & 63, w = t >> 6;
    const int i0 = blockIdx.x * 1024 + t * 4;
    const int v0 = (i0 + 0 < RN) ? cnt[i0 + 0] : 0;
    const int v1 = (i0 + 1 < RN) ? cnt[i0 + 1] : 0;
    const int v2 = (i0 + 2 < RN) ? cnt[i0 + 2] : 0;
    const int v3 = (i0 + 3 < RN) ? cnt[i0 + 3] : 0;
    const int s = v0 + v1 + v2 + v3;
    int sc = s;
    #pragma unroll
    for (int o = 1; o < 64; o <<= 1) { int tmp = __shfl_up(sc, o, 64); if (lane >= o) sc += tmp; }
    if (lane == 63) wsum[w] = sc;
    __syncthreads();
    int woff = 0;
    #pragma unroll
    for (int i = 0; i < 3; ++i) if (i < w) woff += wsum[i];
    int run = woff + sc - s;                 // exclusive within block
    if (i0 + 0 < RN) rp[i0 + 0] = run; run += v0;
    if (i0 + 1 < RN) rp[i0 + 1] = run; run += v1;
    if (i0 + 2 < RN) rp[i0 + 2] = run; run += v2;
    if (i0 + 3 < RN) rp[i0 + 3] = run;
    if (t == 255) bsum[blockIdx.x] = woff + sc;   // block total
}

__global__ __launch_bounds__(256) void scan2_kernel(const int* __restrict__ bsum,
                                                    int* __restrict__ boff,
                                                    int* __restrict__ rp)
{
    __shared__ int wsum[4];
    const int t = threadIdx.x, lane = t & 63, w = t >> 6;
    const int v = (t < SCAN_NB) ? bsum[t] : 0;
    int sc = v;
    #pragma unroll
    for (int o = 1; o < 64; o <<= 1) { int tmp = __shfl_up(sc, o, 64); if (lane >= o) sc += tmp; }
    if (lane == 63) wsum[w] = sc;
    __syncthreads();
    int woff = 0;
    #pragma unroll
    for (int i = 0; i < 3; ++i) if (i < w) woff += wsum[i];
    boff[t] = woff + sc - v;                 // exclusive block offset
    if (t == 0) rp[RN] = E_;                 // total degree == E
}

__global__ __launch_bounds__(256) void scan3_kernel(int* __restrict__ rp,
                                                    const int* __restrict__ boff)
{
    const int off = boff[blockIdx.x];
    if (off == 0) return;
    const int i0 = blockIdx.x * 1024 + threadIdx.x * 4;
    if (i0 + 3 < RN) {
        int4* p = (int4*)(rp + i0);
        int4 q = *p;
        q.x += off; q.y += off; q.z += off; q.w += off;
        *p = q;
    } else {
        for (int i = 0; i < 4; ++i)
            if (i0 + i < RN) rp[i0 + i] += off;
    }
}

// scatter: build packed edge records {dst, edinv, w, 0}
__global__ void scatter_kernel(const int* __restrict__ src, const int* __restrict__ dst,
                               const int* __restrict__ rel, const int* __restrict__ rp,
                               int* __restrict__ fill, const int* __restrict__ deg_i,
                               const float* __restrict__ dinv,
                               int4* __restrict__ csr_pk)
{
    int e = blockIdx.x * 256 + threadIdx.x;
    if (e >= E_) return;
    int s = src[e], r = rel[e], d = dst[e];
    int key = s * R_ + r;
    int pos = rp[key] + atomicAdd(&fill[key], 1);
    float edinv = dinv[key] * dinv[d * R_ + r];
    float w = 1.0f / (float)deg_i[key];
    csr_pk[pos] = make_int4(d, __float_as_int(edinv), __float_as_int(w), 0);
}

// ---------------------------------------------------------------------------
// FUSED gather, per-relation SEGMENTED inner loops (no 5-way predication):
// node-major CSR gives contiguous segments; each segment accumulates its
// tv edge term and fp16 message directly.  csr_pk loads CACHED (re-read
// every iteration, L2-resident); mbuf stores NT (single-use stream).
// ---------------------------------------------------------------------------
__global__ __launch_bounds__(256) void gather_kernel(
    const ushort_t* __restrict__ xh, const int* __restrict__ rp,
    const int* __restrict__ csr_pk_raw,
    const int* __restrict__ act, int k, float* __restrict__ accbuf,
    uint_t* __restrict__ mbuf)
{
    if (act[k] == 0) return;
    const int4v* __restrict__ csr_pk = (const int4v*)csr_pk_raw;
    const int lane = threadIdx.x & 63;
    const int wv = threadIdx.x >> 6;
    const int wid = blockIdx.x * 4 + wv;
    const int nw = gridDim.x * 4;
    float na[5] = {0, 0, 0, 0, 0};
    float ea[5] = {0, 0, 0, 0, 0};
    for (int n = wid; n < N_TOT; n += nw) {
        int barr[6];
        #pragma unroll
        for (int i = 0; i < 6; ++i)
            barr[i] = __builtin_amdgcn_readfirstlane(rp[n * R_ + i]);
        const uint_t vs = ((const uint_t*)(xh + (size_t)n * 128))[lane];
        const float sx = bflo(vs), sy = bfhi(vs);
        const float pp = fmaf(sx, sx, sy * sy);
        #pragma unroll
        for (int r = 0; r < 5; ++r) {
            const int e0 = barr[r];
            const int e1 = barr[r + 1];
            if (e1 > e0) na[r] += pp;
            float dd0 = 0.0f, dd1 = 0.0f, dd2 = 0.0f, dd3 = 0.0f;
            float mxa = 0.0f, mya = 0.0f, mxb = 0.0f, myb = 0.0f;
            int e = e0;
            for (; e + 4 <= e1; e += 4) {
                const int4v p0 = csr_pk[e + 0];
                const int4v p1 = csr_pk[e + 1];
                const int4v p2 = csr_pk[e + 2];
                const int4v p3 = csr_pk[e + 3];
                const uint_t v0 = ((const uint_t*)(xh + (size_t)p0[0] * 128))[lane];
                const uint_t v1 = ((const uint_t*)(xh + (size_t)p1[0] * 128))[lane];
                const uint_t v2 = ((const uint_t*)(xh + (size_t)p2[0] * 128))[lane];
                const uint_t v3 = ((const uint_t*)(xh + (size_t)p3[0] * 128))[lane];
                const float x0 = bflo(v0), y0 = bfhi(v0);
                const float x1 = bflo(v1), y1 = bfhi(v1);
                const float x2 = bflo(v2), y2 = bfhi(v2);
                const float x3 = bflo(v3), y3 = bfhi(v3);
                dd0 = fmaf(__int_as_float(p0[1]), fmaf(sx, x0, sy * y0), dd0);
                dd1 = fmaf(__int_as_float(p1[1]), fmaf(sx, x1, sy * y1), dd1);
                dd2 = fmaf(__int_as_float(p2[1]), fmaf(sx, x2, sy * y2), dd2);
                dd3 = fmaf(__int_as_float(p3[1]), fmaf(sx, x3, sy * y3), dd3);
                const float w0 = __int_as_float(p0[2]);
                const float w1 = __int_as_float(p1[2]);
                const float w2 = __int_as_float(p2[2]);
                const float w3 = __int_as_float(p3[2]);
                mxa = fmaf(w0, x0, mxa); mya = fmaf(w0, y0, mya);
                mxb = fmaf(w1, x1, mxb); myb = fmaf(w1, y1, myb);
                mxa = fmaf(w2, x2, mxa); mya = fmaf(w2, y2, mya);
                mxb = fmaf(w3, x3, mxb); myb = fmaf(w3, y3, myb);
            }
            for (; e + 2 <= e1; e += 2) {
                const int4v p0 = csr_pk[e + 0];
                const int4v p1 = csr_pk[e + 1];
                const uint_t v0 = ((const uint_t*)(xh + (size_t)p0[0] * 128))[lane];
                const uint_t v1 = ((const uint_t*)(xh + (size_t)p1[0] * 128))[lane];
                const float x0 = bflo(v0), y0 = bfhi(v0);
                const float x1 = bflo(v1), y1 = bfhi(v1);
                dd0 = fmaf(__int_as_float(p0[1]), fmaf(sx, x0, sy * y0), dd0);
                dd1 = fmaf(__int_as_float(p1[1]), fmaf(sx, x1, sy * y1), dd1);
                const float w0 = __int_as_float(p0[2]);
                const float w1 = __int_as_float(p1[2]);
                mxa = fmaf(w0, x0, mxa); mya = fmaf(w0, y0, mya);
                mxb = fmaf(w1, x1, mxb); myb = fmaf(w1, y1, myb);
            }
            if (e < e1) {
                const int4v p0 = csr_pk[e];
                const uint_t v0 = ((const uint_t*)(xh + (size_t)p0[0] * 128))[lane];
                const float x0 = bflo(v0), y0 = bfhi(v0);
                dd0 = fmaf(__int_as_float(p0[1]), fmaf(sx, x0, sy * y0), dd0);
                const float w0 = __int_as_float(p0[2]);
                mxa = fmaf(w0, x0, mxa); mya = fmaf(w0, y0, mya);
            }
            ea[r] += (dd0 + dd1) + (dd2 + dd3);
            __half2 hm = __floats2half2_rn(mxa + mxb, mya + myb);
            __builtin_nontemporal_store(*reinterpret_cast<const uint_t*>(&hm),
                mbuf + (size_t)r * NL_ + (size_t)n * 64 + lane);
        }
    }
    __shared__ float sacc[4][10];
    #pragma unroll
    for (int r = 0; r < 5; ++r) {
        float a = na[r], b = ea[r];
        for (int o = 32; o > 0; o >>= 1) {
            a += __shfl_down(a, o, 64);
            b += __shfl_down(b, o, 64);
        }
        if (lane == 0) { sacc[wv][r] = a; sacc[wv][5 + r] = b; }
    }
    __syncthreads();
    if (threadIdx.x < 10) {
        float t = sacc[0][threadIdx.x] + sacc[1][threadIdx.x] +
                  sacc[2][threadIdx.x] + sacc[3][threadIdx.x];
        atomicAdd(&accbuf[k * 16 + threadIdx.x], t);
    }
}

// ---------------------------------------------------------------------------
// scalar: fp32 lane-parallel mirror descent (lanes 0..7 of ONE wave).
// ---------------------------------------------------------------------------
__global__ void scalar_kernel(const float* __restrict__ accbuf, float* __restrict__ ug,
                              float* __restrict__ c_l1, int* __restrict__ act, int k)
{
    if (blockIdx.x != 0 || threadIdx.x >= 8) return;
    const int r = threadIdx.x;
    const int a = act[k];
    float w = (r < 5) ? (accbuf[k * 16 + r] - accbuf[k * 16 + 5 + r]) * (1.0f / 30000.0f)
                      : 0.0f;
    float l1 = fabsf(w);
    for (int o = 4; o > 0; o >>= 1) l1 += __shfl_xor(l1, o, 8);
    if (k == 0 && r == 0) c_l1[0] = l1;
    if (!a) { if (r == 0) act[k + 1] = 0; return; }
    float u = (r < 5) ? ug[r] : 0.0f;
    const float fi = l1 + 3.0f;
    bool mact = true;
    for (int t = 1; t <= 20; ++t) {
        float T = sqrtf(3.2188758248682006f / ((float)t * fi * fi));
        float ta = u * expf(-T * (3.0f * u + w));
        float ssum = ta;
        for (int o = 4; o > 0; o >>= 1) ssum += __shfl_xor(ssum, o, 8);
        float un = ta / ssum;
        float d0 = u - un;
        float dq = d0 * d0;
        for (int o = 4; o > 0; o >>= 1) dq += __shfl_xor(dq, o, 8);
        if (mact) u = un;
        mact = mact && (sqrtf(dq) >= 1e-3f);
    }
    if (r < 5) ug[r] = u;
    if (r == 0) act[k + 1] = (l1 / c_l1[0] >= 0.3f) ? 1 : 0;
}

// ---------------------------------------------------------------------------
// apply: x = x/21 + (20/21)*sum_r u_r m_r — pure streaming with NT hints.
// ---------------------------------------------------------------------------
__global__ __launch_bounds__(256) void apply_kernel(
    float* __restrict__ x, ushort_t* __restrict__ xh_out,
    const uint_t* __restrict__ mbuf, const float* __restrict__ ug,
    const int* __restrict__ act, int k)
{
    if (act[k + 1] == 0) return;
    const int tid = blockIdx.x * 256 + threadIdx.x;
    if (tid >= NL_) return;
    const float u0 = ug[0], u1 = ug[1], u2 = ug[2], u3 = ug[3], u4 = ug[4];

    uint_t w0 = __builtin_nontemporal_load(mbuf + (size_t)0 * NL_ + tid);
    uint_t w1 = __builtin_nontemporal_load(mbuf + (size_t)1 * NL_ + tid);
    uint_t w2 = __builtin_nontemporal_load(mbuf + (size_t)2 * NL_ + tid);
    uint_t w3 = __builtin_nontemporal_load(mbuf + (size_t)3 * NL_ + tid);
    uint_t w4 = __builtin_nontemporal_load(mbuf + (size_t)4 * NL_ + tid);
    const float2 m0 = __half22float2(*reinterpret_cast<const __half2*>(&w0));
    const float2 m1 = __half22float2(*reinterpret_cast<const __half2*>(&w1));
    const float2 m2 = __half22float2(*reinterpret_cast<const __half2*>(&w2));
    const float2 m3 = __half22float2(*reinterpret_cast<const __half2*>(&w3));
    const float2 m4 = __half22float2(*reinterpret_cast<const __half2*>(&w4));

    const float sm_x = u0 * m0.x + u1 * m1.x + u2 * m2.x + u3 * m3.x + u4 * m4.x;
    const float sm_y = u0 * m0.y + u1 * m1.y + u2 * m2.y + u3 * m3.y + u4 * m4.y;

    const float ci = 1.0f / 21.0f, cb = 20.0f / 21.0f;
    f32x2* xp = (f32x2*)x;
    const f32x2 xs = __builtin_nontemporal_load(xp + tid);
    const float nx_ = fmaf(cb, sm_x, xs[0] * ci);
    const float ny_ = fmaf(cb, sm_y, xs[1] * ci);
    f32x2 xn; xn[0] = nx_; xn[1] = ny_;
    __builtin_nontemporal_store(xn, xp + tid);
    ((uint_t*)xh_out)[tid] = ((uint_t)f2bf(ny_) << 16) | (uint_t)f2bf(nx_);
}

// ---------------------------------------------------------------------------
// epilogue: logits = x@Wout + bout ; write logits, x, u
// ---------------------------------------------------------------------------
__global__ __launch_bounds__(256) void final_kernel(const float* __restrict__ x,
                                                    const float* __restrict__ Wout,
                                                    const float* __restrict__ bout,
                                                    const float* __restrict__ ug,
                                                    float* __restrict__ out)
{
    const int nl = threadIdx.x >> 7;
    const int n = blockIdx.x * 2 + nl;
    const int j = threadIdx.x & 127;
    const int lane = threadIdx.x & 63;
    const int wv = threadIdx.x >> 6;
    float xv = x[(size_t)n * 128 + j];
    out[(size_t)NC_ + (size_t)n * 128 + j] = xv;
    float p[8];
    #pragma unroll
    for (int c = 0; c < 8; ++c) p[c] = xv * Wout[j * 8 + c];
    #pragma unroll
    for (int c = 0; c < 8; ++c)
        for (int o = 32; o > 0; o >>= 1) p[c] += __shfl_down(p[c], o, 64);
    __shared__ float sp[4][8];
    if (lane == 0) {
        #pragma unroll
        for (int c = 0; c < 8; ++c) sp[wv][c] = p[c];
    }
    __syncthreads();
    if (j < 8) {
        int c = j;
        out[(size_t)n * 8 + c] = bout[c] + sp[2 * nl][c] + sp[2 * nl + 1][c];
    }
    if (blockIdx.x == 0 && threadIdx.x < 5)
        out[(size_t)NC_ + (size_t)NX_ + threadIdx.x] = ug[threadIdx.x];
}

// ---------------------------------------------------------------------------
extern "C" void kernel_launch(void* const* d_in, const int* in_sizes, int n_in,
                              void* d_out, int out_size, void* d_ws, size_t ws_size,
                              hipStream_t stream)
{
    const float* feat0 = (const float*)d_in[0];
    const float* feat1 = (const float*)d_in[1];
    const float* W0   = (const float*)d_in[2];
    const float* b0   = (const float*)d_in[3];
    const float* W1   = (const float*)d_in[4];
    const float* b1   = (const float*)d_in[5];
    const float* Wm1  = (const float*)d_in[6];
    const float* bm1  = (const float*)d_in[7];
    const float* Wm2  = (const float*)d_in[8];
    const float* bm2  = (const float*)d_in[9];
    const float* Wout = (const float*)d_in[10];
    const float* bout = (const float*)d_in[11];
    const int* src = (const int*)d_in[12];
    const int* dst = (const int*)d_in[13];
    const int* rel = (const int*)d_in[14];
    float* out = (float*)d_out;

    char* p = (char*)d_ws;
    auto alloc = [&](size_t bytes) { char* q = p; p += (bytes + 255) & ~(size_t)255; return q; };
    float*    xbuf      = (float*)   alloc((size_t)NX_ * 4);
    ushort_t* xh0       = (ushort_t*)alloc((size_t)NX_ * 2);
    ushort_t* xh1       = (ushort_t*)alloc((size_t)NX_ * 2);
    uint_t*   mbuf      = (uint_t*)  alloc((size_t)R_ * NL_ * 4);   // 38.4 MB fp16 msgs
    ushort_t* fb0       = (ushort_t*)alloc((size_t)N0_ * 256 * 2);
    ushort_t* fb1       = (ushort_t*)alloc((size_t)(N_TOT - N0_) * 128 * 2);
    ushort_t* wt0       = (ushort_t*)alloc((size_t)128 * 256 * 2);
    ushort_t* wt1       = (ushort_t*)alloc((size_t)128 * 128 * 2);
    ushort_t* wtm1      = (ushort_t*)alloc((size_t)128 * 128 * 2);
    ushort_t* wtm2      = (ushort_t*)alloc((size_t)128 * 128 * 2);
    int*      deg_i     = (int*)     alloc((size_t)RN * 4);
    float*    dinv      = (float*)   alloc((size_t)RN * 4);
    int*      rp        = (int*)     alloc(((size_t)RN + 1) * 4);
    int*      fill      = (int*)     alloc((size_t)RN * 4);
    int*      bsum      = (int*)     alloc((size_t)SCAN_NB * 4);
    int*      boff      = (int*)     alloc(256 * 4);
    int4*     csr_pk    = (int4*)    alloc((size_t)E_ * 16);
    float*    accbuf    = (float*)   alloc(128 * 4);
    float*    ug        = (float*)   alloc(64);
    float*    c_l1      = (float*)   alloc(64);
    int*      act       = (int*)     alloc(64);

    hipMemsetAsync(deg_i, 0, (size_t)RN * 4, stream);
    hipMemsetAsync(fill, 0, (size_t)RN * 4, stream);
    hipMemsetAsync(accbuf, 0, 128 * 4, stream);
    init_kernel<<<1, 64, 0, stream>>>(ug, act);

    // bf16 pre-conversion
    cvtfeat_kernel<<<(N0_ * 256 / 4 + 255) / 256, 256, 0, stream>>>(feat0, fb0, N0_ * 256);
    cvtfeat_kernel<<<((N_TOT - N0_) * 128 / 4 + 255) / 256, 256, 0, stream>>>(
        feat1, fb1, (N_TOT - N0_) * 128);
    cvtw_kernel<<<(128 * 256 + 255) / 256, 256, 0, stream>>>(W0, wt0, 256);
    cvtw_kernel<<<(128 * 128 + 255) / 256, 256, 0, stream>>>(W1, wt1, 128);
    cvtw_kernel<<<(128 * 128 + 255) / 256, 256, 0, stream>>>(Wm1, wtm1, 128);
    cvtw_kernel<<<(128 * 128 + 255) / 256, 256, 0, stream>>>(Wm2, wtm2, 128);

    mlp_mfma_kernel<<<(N_TOT + 31) / 32, 256, 0, stream>>>(
        fb0, fb1, wt0, wt1, wtm1, wtm2, b0, b1, bm1, bm2, xbuf, xh0);

    deg_kernel<<<(E_ + 255) / 256, 256, 0, stream>>>(src, rel, deg_i);
    dinv_kernel<<<(RN + 255) / 256, 256, 0, stream>>>(deg_i, dinv);
    scan1_kernel<<<SCAN_NB, 256, 0, stream>>>(deg_i, rp, bsum);
    scan2_kernel<<<1, 256, 0, stream>>>(bsum, boff, rp);
    scan3_kernel<<<SCAN_NB, 256, 0, stream>>>(rp, boff);
    scatter_kernel<<<(E_ + 255) / 256, 256, 0, stream>>>(src, dst, rel, rp, fill,
                                                         deg_i, dinv, csr_pk);

    ushort_t* ha = xh0;
    ushort_t* hb = xh1;
    for (int k = 0; k < 8; ++k) {
        gather_kernel<<<2500, 256, 0, stream>>>(ha, rp, (const int*)csr_pk,
                                                act, k, accbuf, mbuf);
        scalar_kernel<<<1, 64, 0, stream>>>(accbuf, ug, c_l1, act, k);
        apply_kernel<<<(NL_ + 255) / 256, 256, 0, stream>>>(xbuf, hb, mbuf, ug, act, k);
        ushort_t* t = ha; ha = hb; hb = t;
    }

    final_kernel<<<N_TOT / 2, 256, 0, stream>>>(xbuf, Wout, bout, ug, out);
}

// Round 12
// 436.114 us; speedup vs baseline: 1.0178x; 1.0178x over previous
//
#include <hip/hip_runtime.h>
#include <hip/hip_fp16.h>
#include <cmath>

typedef unsigned short ushort_t;
typedef unsigned int uint_t;

#define N_TOT 30000
#define N0_   18000
#define R_    5
#define E_    600000
#define RN    (R_ * N_TOT)
#define NC_   (N_TOT * 8)        // logits elements
#define NX_   (N_TOT * 128)      // x elements
#define NL_   (N_TOT * 64)      // node*lane pairs
#define SCAN_NB ((RN + 1023) / 1024)   // 147 blocks of 1024 elements

typedef __attribute__((ext_vector_type(8))) short bf16x8;
typedef __attribute__((ext_vector_type(4))) float f32x4;
typedef __attribute__((ext_vector_type(2))) float f32x2;

__device__ __forceinline__ ushort_t f2bf(float f) {
    uint_t u = __float_as_uint(f);
    uint_t r = (u + 0x7fffu + ((u >> 16) & 1u)) >> 16;   // RTNE
    return (ushort_t)r;
}
__device__ __forceinline__ float bflo(uint_t v) { return __uint_as_float(v << 16); }
__device__ __forceinline__ float bfhi(uint_t v) { return __uint_as_float(v & 0xffff0000u); }

// ---------------------------------------------------------------------------
// init: u = 1/R, act[0]=1, act[1..15]=0
// ---------------------------------------------------------------------------
__global__ void init_kernel(float* ug, int* act) {
    if (threadIdx.x < 16) act[threadIdx.x] = (threadIdx.x == 0) ? 1 : 0;
    if (threadIdx.x < 5) ug[threadIdx.x] = 0.2f;
}

// ---------------------------------------------------------------------------
// bf16 pre-conversion: feats row-major, weights transposed [col][k]
// ---------------------------------------------------------------------------
__global__ __launch_bounds__(256) void cvtfeat_kernel(const float* __restrict__ in,
                                                      ushort_t* __restrict__ out,
                                                      int nelem)
{
    int i = (blockIdx.x * 256 + threadIdx.x) * 4;
    if (i >= nelem) return;
    const float4 v = *(const float4*)(in + i);
    ushort_t o0 = f2bf(v.x), o1 = f2bf(v.y), o2 = f2bf(v.z), o3 = f2bf(v.w);
    uint_t p0 = (uint_t)o0 | ((uint_t)o1 << 16);
    uint_t p1 = (uint_t)o2 | ((uint_t)o3 << 16);
    uint2* op = (uint2*)(out + i);
    *op = make_uint2(p0, p1);
}

__global__ __launch_bounds__(256) void cvtw_kernel(const float* __restrict__ W,
                                                   ushort_t* __restrict__ wt, int K)
{
    int idx = blockIdx.x * 256 + threadIdx.x;   // idx = j*K + k
    if (idx >= 128 * K) return;
    int j = idx / K, k = idx - j * K;
    wt[idx] = f2bf(W[k * 128 + j]);
}

// ---------------------------------------------------------------------------
// MFMA MLP: 32 nodes per 256-thread block (4 waves) — unchanged.
// ---------------------------------------------------------------------------
__global__ __launch_bounds__(256) void mlp_mfma_kernel(
    const ushort_t* __restrict__ fb0, const ushort_t* __restrict__ fb1,
    const ushort_t* __restrict__ wt0, const ushort_t* __restrict__ wt1,
    const ushort_t* __restrict__ wtm1, const ushort_t* __restrict__ wtm2,
    const float* __restrict__ b0, const float* __restrict__ b1,
    const float* __restrict__ bm1, const float* __restrict__ bm2,
    float* __restrict__ xout, ushort_t* __restrict__ xh)
{
    const int t = threadIdx.x;
    const int lane = t & 63;
    const int wv = t >> 6;            // 0..3 -> col block wv*32
    const int lr = lane & 15;         // A-row / B-col within tile
    const int lg = lane >> 4;         // k-group, D row-group
    const int row0 = blockIdx.x * 32;

    __shared__ ushort_t hls[32][136];   // bf16 h   (pad: 272B row stride)
    __shared__ float    tls[32][132];   // fp32 t1/t2 (pad: 528B row stride)
    __shared__ ushort_t zls[32][136];   // bf16 z

    // ---------------- GEMM1: h = feat @ W + b -------------------------------
    #pragma unroll
    for (int mt = 0; mt < 2; ++mt) {
        const int rb = row0 + mt * 16;
        const bool is0 = (rb < N0_);
        const int r = min(rb + lr, N_TOT - 1);
        const ushort_t* __restrict__ fa =
            is0 ? fb0 + (size_t)r * 256 : fb1 + (size_t)(r - N0_) * 128;
        const ushort_t* __restrict__ wt = is0 ? wt0 : wt1;
        const int K = is0 ? 256 : 128;
        const int c0 = wv * 32 + lr;

        f32x4 a0 = {0.f, 0.f, 0.f, 0.f};
        f32x4 a1 = {0.f, 0.f, 0.f, 0.f};
        for (int ks = 0; ks < K; ks += 32) {
            const bf16x8 af = *(const bf16x8*)(fa + ks + lg * 8);
            const bf16x8 wb0 = *(const bf16x8*)(wt + (size_t)c0 * K + ks + lg * 8);
            const bf16x8 wb1 = *(const bf16x8*)(wt + (size_t)(c0 + 16) * K + ks + lg * 8);
            a0 = __builtin_amdgcn_mfma_f32_16x16x32_bf16(af, wb0, a0, 0, 0, 0);
            a1 = __builtin_amdgcn_mfma_f32_16x16x32_bf16(af, wb1, a1, 0, 0, 0);
        }
        const float bb0 = is0 ? b0[c0] : b1[c0];
        const float bb1 = is0 ? b0[c0 + 16] : b1[c0 + 16];
        #pragma unroll
        for (int j = 0; j < 4; ++j) {
            hls[mt * 16 + lg * 4 + j][c0]      = f2bf(a0[j] + bb0);
            hls[mt * 16 + lg * 4 + j][c0 + 16] = f2bf(a1[j] + bb1);
        }
    }
    __syncthreads();

    // ---------------- GEMM2: t1 = h @ Wm1 + bm1 -----------------------------
    {
        const int c0 = wv * 32 + lr;
        f32x4 g00 = {0.f,0.f,0.f,0.f}, g01 = {0.f,0.f,0.f,0.f};
        f32x4 g10 = {0.f,0.f,0.f,0.f}, g11 = {0.f,0.f,0.f,0.f};
        for (int ks = 0; ks < 128; ks += 32) {
            const bf16x8 wb0 = *(const bf16x8*)(wtm1 + (size_t)c0 * 128 + ks + lg * 8);
            const bf16x8 wb1 = *(const bf16x8*)(wtm1 + (size_t)(c0 + 16) * 128 + ks + lg * 8);
            const bf16x8 af0 = *(const bf16x8*)(&hls[lr][ks + lg * 8]);
            const bf16x8 af1 = *(const bf16x8*)(&hls[16 + lr][ks + lg * 8]);
            g00 = __builtin_amdgcn_mfma_f32_16x16x32_bf16(af0, wb0, g00, 0, 0, 0);
            g01 = __builtin_amdgcn_mfma_f32_16x16x32_bf16(af0, wb1, g01, 0, 0, 0);
            g10 = __builtin_amdgcn_mfma_f32_16x16x32_bf16(af1, wb0, g10, 0, 0, 0);
            g11 = __builtin_amdgcn_mfma_f32_16x16x32_bf16(af1, wb1, g11, 0, 0, 0);
        }
        const float bb0 = bm1[c0], bb1 = bm1[c0 + 16];
        #pragma unroll
        for (int j = 0; j < 4; ++j) {
            tls[lg * 4 + j][c0]           = g00[j] + bb0;
            tls[lg * 4 + j][c0 + 16]      = g01[j] + bb1;
            tls[16 + lg * 4 + j][c0]      = g10[j] + bb0;
            tls[16 + lg * 4 + j][c0 + 16] = g11[j] + bb1;
        }
    }
    __syncthreads();

    // ---------------- LN + relu -> z (bf16) ---------------------------------
    {
        const int row = t >> 3, seg = t & 7;
        f32x4 v[4];
        float s = 0.f;
        #pragma unroll
        for (int i = 0; i < 4; ++i) {
            v[i] = *(const f32x4*)(&tls[row][seg * 16 + i * 4]);
            s += v[i][0] + v[i][1] + v[i][2] + v[i][3];
        }
        #pragma unroll
        for (int o = 1; o < 8; o <<= 1) s += __shfl_xor(s, o, 64);
        const float mean = s * (1.0f / 128.0f);
        float q = 0.f;
        #pragma unroll
        for (int i = 0; i < 4; ++i) {
            #pragma unroll
            for (int e = 0; e < 4; ++e) { float d = v[i][e] - mean; q = fmaf(d, d, q); }
        }
        #pragma unroll
        for (int o = 1; o < 8; o <<= 1) q += __shfl_xor(q, o, 64);
        const float inv = 1.0f / sqrtf(q * (1.0f / 128.0f) + 1e-5f);
        uint_t* zp = (uint_t*)&zls[row][0];
        #pragma unroll
        for (int i = 0; i < 4; ++i) {
            ushort_t z0 = f2bf(fmaxf((v[i][0] - mean) * inv, 0.0f));
            ushort_t z1 = f2bf(fmaxf((v[i][1] - mean) * inv, 0.0f));
            ushort_t z2 = f2bf(fmaxf((v[i][2] - mean) * inv, 0.0f));
            ushort_t z3 = f2bf(fmaxf((v[i][3] - mean) * inv, 0.0f));
            zp[(seg * 16 + i * 4) / 2]     = (uint_t)z0 | ((uint_t)z1 << 16);
            zp[(seg * 16 + i * 4) / 2 + 1] = (uint_t)z2 | ((uint_t)z3 << 16);
        }
    }
    __syncthreads();

    // ---------------- GEMM3: t2 = z @ Wm2 + bm2 -----------------------------
    {
        const int c0 = wv * 32 + lr;
        f32x4 g00 = {0.f,0.f,0.f,0.f}, g01 = {0.f,0.f,0.f,0.f};
        f32x4 g10 = {0.f,0.f,0.f,0.f}, g11 = {0.f,0.f,0.f,0.f};
        for (int ks = 0; ks < 128; ks += 32) {
            const bf16x8 wb0 = *(const bf16x8*)(wtm2 + (size_t)c0 * 128 + ks + lg * 8);
            const bf16x8 wb1 = *(const bf16x8*)(wtm2 + (size_t)(c0 + 16) * 128 + ks + lg * 8);
            const bf16x8 af0 = *(const bf16x8*)(&zls[lr][ks + lg * 8]);
            const bf16x8 af1 = *(const bf16x8*)(&zls[16 + lr][ks + lg * 8]);
            g00 = __builtin_amdgcn_mfma_f32_16x16x32_bf16(af0, wb0, g00, 0, 0, 0);
            g01 = __builtin_amdgcn_mfma_f32_16x16x32_bf16(af0, wb1, g01, 0, 0, 0);
            g10 = __builtin_amdgcn_mfma_f32_16x16x32_bf16(af1, wb0, g10, 0, 0, 0);
            g11 = __builtin_amdgcn_mfma_f32_16x16x32_bf16(af1, wb1, g11, 0, 0, 0);
        }
        __syncthreads();   // all zls reads done before tls is overwritten below
        const float bb0 = bm2[c0], bb1 = bm2[c0 + 16];
        #pragma unroll
        for (int j = 0; j < 4; ++j) {
            tls[lg * 4 + j][c0]           = g00[j] + bb0;
            tls[lg * 4 + j][c0 + 16]      = g01[j] + bb1;
            tls[16 + lg * 4 + j][c0]      = g10[j] + bb0;
            tls[16 + lg * 4 + j][c0 + 16] = g11[j] + bb1;
        }
    }
    __syncthreads();

    // ---------------- per-row standardization + store -----------------------
    {
        const int row = t >> 3, seg = t & 7;
        const int n = row0 + row;
        f32x4 v[4];
        float s = 0.f;
        #pragma unroll
        for (int i = 0; i < 4; ++i) {
            v[i] = *(const f32x4*)(&tls[row][seg * 16 + i * 4]);
            s += v[i][0] + v[i][1] + v[i][2] + v[i][3];
        }
        #pragma unroll
        for (int o = 1; o < 8; o <<= 1) s += __shfl_xor(s, o, 64);
        const float mu = s * (1.0f / 128.0f);
        float q = 0.f;
        #pragma unroll
        for (int i = 0; i < 4; ++i) {
            #pragma unroll
            for (int e = 0; e < 4; ++e) { float d = v[i][e] - mu; q = fmaf(d, d, q); }
        }
        #pragma unroll
        for (int o = 1; o < 8; o <<= 1) q += __shfl_xor(q, o, 64);
        const float sd = sqrtf(q * (1.0f / 127.0f));
        const float inv = 1.0f / sd;
        if (n < N_TOT) {
            uint_t* xhp = (uint_t*)xh + (size_t)n * 64 + seg * 8;
            float* xop = xout + (size_t)n * 128 + seg * 16;
            #pragma unroll
            for (int i = 0; i < 4; ++i) {
                float rr[4];
                #pragma unroll
                for (int e = 0; e < 4; ++e) {
                    float r = (v[i][e] - mu) * inv;
                    if (!(fabsf(r) <= 3.402823466e38f)) {
                        r = (r != r) ? 0.0f : ((r > 0.0f) ? 3.402823466e38f : -3.402823466e38f);
                    }
                    rr[e] = r;
                }
                *(float4*)(xop + i * 4) = make_float4(rr[0], rr[1], rr[2], rr[3]);
                xhp[i * 2]     = (uint_t)f2bf(rr[0]) | ((uint_t)f2bf(rr[1]) << 16);
                xhp[i * 2 + 1] = (uint_t)f2bf(rr[2]) | ((uint_t)f2bf(rr[3]) << 16);
            }
        }
    }
}

// ---------------------------------------------------------------------------
// preprocessing — node-major keys: key = src*5 + rel
// ---------------------------------------------------------------------------
__global__ void deg_kernel(const int* __restrict__ src, const int* __restrict__ rel,
                           int* __restrict__ deg_i)
{
    int e = blockIdx.x * 256 + threadIdx.x;
    if (e >= E_) return;
    atomicAdd(&deg_i[src[e] * R_ + rel[e]], 1);
}

// 3-pass parallel exclusive scan over RN elements
__global__ __launch_bounds__(256) void scan1_kernel(const int* __restrict__ cnt,
                                                    int* __restrict__ rp,
                                                    int* __restrict__ bsum)
{
    __shared__ int wsum[4];
    const int t = threadIdx.x, lane = t & 63, w = t >> 6;
    const int i0 = blockIdx.x * 1024 + t * 4;
    const int v0 = (i0 + 0 < RN) ? cnt[i0 + 0] : 0;
    const int v1 = (i0 + 1 < RN) ? cnt[i0 + 1] : 0;
    const int v2 = (i0 + 2 < RN) ? cnt[i0 + 2] : 0;
    const int v3 = (i0 + 3 < RN) ? cnt[i0 + 3] : 0;
    const int s = v0 + v1 + v2 + v3;
    int sc = s;
    #pragma unroll
    for (int o = 1; o < 64; o <<= 1) { int tmp = __shfl_up(sc, o, 64); if (lane >= o) sc += tmp; }
    if (lane == 63) wsum[w] = sc;
    __syncthreads();
    int woff = 0;
    #pragma unroll
    for (int i = 0; i < 3; ++i) if (i < w) woff += wsum[i];
    int run = woff + sc - s;                 // exclusive within block
    if (i0 + 0 < RN) rp[i0 + 0] = run; run += v0;
    if (i0 + 1 < RN) rp[i0 + 1] = run; run += v1;
    if (i0 + 2 < RN) rp[i0 + 2] = run; run += v2;
    if (i0 + 3 < RN) rp[i0 + 3] = run;
    if (t == 255) bsum[blockIdx.x] = woff + sc;   // block total
}

__global__ __launch_bounds__(256) void scan2_kernel(const int* __restrict__ bsum,
                                                    int* __restrict__ boff,
                                                    int* __restrict__ rp)
{
    __shared__ int wsum[4];
    const int t = threadIdx.x, lane = t & 63, w = t >> 6;
    const int v = (t < SCAN_NB) ? bsum[t] : 0;
    int sc = v;
    #pragma unroll
    for (int o = 1; o < 64; o <<= 1) { int tmp = __shfl_up(sc, o, 64); if (lane >= o) sc += tmp; }
    if (lane == 63) wsum[w] = sc;
    __syncthreads();
    int woff = 0;
    #pragma unroll
    for (int i = 0; i < 3; ++i) if (i < w) woff += wsum[i];
    boff[t] = woff + sc - v;                 // exclusive block offset
    if (t == 0) rp[RN] = E_;                 // total degree == E
}

__global__ __launch_bounds__(256) void scan3_kernel(int* __restrict__ rp,
                                                    const int* __restrict__ boff)
{
    const int off = boff[blockIdx.x];
    if (off == 0) return;
    const int i0 = blockIdx.x * 1024 + threadIdx.x * 4;
    if (i0 + 3 < RN) {
        int4* p = (int4*)(rp + i0);
        int4 q = *p;
        q.x += off; q.y += off; q.z += off; q.w += off;
        *p = q;
    } else {
        for (int i = 0; i < 4; ++i)
            if (i0 + i < RN) rp[i0 + i] += off;
    }
}

// scatter: build packed edge records {dst, edinv, w, 0}; dinv computed inline
__global__ void scatter_kernel(const int* __restrict__ src, const int* __restrict__ dst,
                               const int* __restrict__ rel, const int* __restrict__ rp,
                               int* __restrict__ fill, const int* __restrict__ deg_i,
                               int4* __restrict__ csr_pk)
{
    int e = blockIdx.x * 256 + threadIdx.x;
    if (e >= E_) return;
    int s = src[e], r = rel[e], d = dst[e];
    int key = s * R_ + r;
    int pos = rp[key] + atomicAdd(&fill[key], 1);
    int dg_s = deg_i[key];
    int dg_d = deg_i[d * R_ + r];
    float di_s = (dg_s > 0) ? 1.0f / sqrtf((float)dg_s) : 0.0f;
    float di_d = (dg_d > 0) ? 1.0f / sqrtf((float)dg_d) : 0.0f;
    float edinv = di_s * di_d;
    float w = 1.0f / (float)dg_s;
    csr_pk[pos] = make_int4(d, __float_as_int(edinv), __float_as_int(w), 0);
}

// ---------------------------------------------------------------------------
// FUSED gather (R8-proven structure): merged edge loop over all 5 relation
// segments, unroll x4, predicated per-relation binning, CACHED csr_pk loads
// (re-read every iteration, L2-resident), plain mbuf stores.  Grid 2500 ->
// exactly 3 nodes per wave.
// ---------------------------------------------------------------------------
__global__ __launch_bounds__(256) void gather_kernel(
    const ushort_t* __restrict__ xh, const int* __restrict__ rp,
    const int4* __restrict__ csr_pk,
    const int* __restrict__ act, int k, float* __restrict__ accbuf,
    uint_t* __restrict__ mbuf)
{
    if (act[k] == 0) return;
    const int lane = threadIdx.x & 63;
    const int wv = threadIdx.x >> 6;
    const int wid = blockIdx.x * 4 + wv;
    const int nw = gridDim.x * 4;
    float na[5] = {0, 0, 0, 0, 0};
    float ea[5] = {0, 0, 0, 0, 0};
    for (int n = wid; n < N_TOT; n += nw) {
        const int b0 = __builtin_amdgcn_readfirstlane(rp[n * R_ + 0]);
        const int b1 = __builtin_amdgcn_readfirstlane(rp[n * R_ + 1]);
        const int b2 = __builtin_amdgcn_readfirstlane(rp[n * R_ + 2]);
        const int b3 = __builtin_amdgcn_readfirstlane(rp[n * R_ + 3]);
        const int b4 = __builtin_amdgcn_readfirstlane(rp[n * R_ + 4]);
        const int b5 = __builtin_amdgcn_readfirstlane(rp[n * R_ + 5]);
        const uint_t vs = ((const uint_t*)(xh + (size_t)n * 128))[lane];
        const float sx = bflo(vs), sy = bfhi(vs);
        const float pp = fmaf(sx, sx, sy * sy);
        if (b1 > b0) na[0] += pp;
        if (b2 > b1) na[1] += pp;
        if (b3 > b2) na[2] += pp;
        if (b4 > b3) na[3] += pp;
        if (b5 > b4) na[4] += pp;
        float mx[5] = {0, 0, 0, 0, 0};
        float my[5] = {0, 0, 0, 0, 0};
        int e = b0;
        for (; e + 4 <= b5; e += 4) {
            int4 p0 = csr_pk[e + 0];
            int4 p1 = csr_pk[e + 1];
            int4 p2 = csr_pk[e + 2];
            int4 p3 = csr_pk[e + 3];
            const uint_t v0 = ((const uint_t*)(xh + (size_t)p0.x * 128))[lane];
            const uint_t v1 = ((const uint_t*)(xh + (size_t)p1.x * 128))[lane];
            const uint_t v2 = ((const uint_t*)(xh + (size_t)p2.x * 128))[lane];
            const uint_t v3 = ((const uint_t*)(xh + (size_t)p3.x * 128))[lane];
            const float x0 = bflo(v0), y0 = bfhi(v0);
            const float x1 = bflo(v1), y1 = bfhi(v1);
            const float x2 = bflo(v2), y2 = bfhi(v2);
            const float x3 = bflo(v3), y3 = bfhi(v3);
            const float d0 = __int_as_float(p0.y) * fmaf(sx, x0, sy * y0);
            const float d1 = __int_as_float(p1.y) * fmaf(sx, x1, sy * y1);
            const float d2 = __int_as_float(p2.y) * fmaf(sx, x2, sy * y2);
            const float d3 = __int_as_float(p3.y) * fmaf(sx, x3, sy * y3);
            const int r0 = (e + 0 >= b1) + (e + 0 >= b2) + (e + 0 >= b3) + (e + 0 >= b4);
            const int r1 = (e + 1 >= b1) + (e + 1 >= b2) + (e + 1 >= b3) + (e + 1 >= b4);
            const int r2 = (e + 2 >= b1) + (e + 2 >= b2) + (e + 2 >= b3) + (e + 2 >= b4);
            const int r3 = (e + 3 >= b1) + (e + 3 >= b2) + (e + 3 >= b3) + (e + 3 >= b4);
            #pragma unroll
            for (int rr = 0; rr < 5; ++rr) {
                ea[rr] += (r0 == rr ? d0 : 0.0f) + (r1 == rr ? d1 : 0.0f) +
                          (r2 == rr ? d2 : 0.0f) + (r3 == rr ? d3 : 0.0f);
                const float ws0 = (r0 == rr) ? __int_as_float(p0.z) : 0.0f;
                const float ws1 = (r1 == rr) ? __int_as_float(p1.z) : 0.0f;
                const float ws2 = (r2 == rr) ? __int_as_float(p2.z) : 0.0f;
                const float ws3 = (r3 == rr) ? __int_as_float(p3.z) : 0.0f;
                mx[rr] = fmaf(ws0, x0, fmaf(ws1, x1, fmaf(ws2, x2, fmaf(ws3, x3, mx[rr]))));
                my[rr] = fmaf(ws0, y0, fmaf(ws1, y1, fmaf(ws2, y2, fmaf(ws3, y3, my[rr]))));
            }
        }
        for (; e < b5; ++e) {
            int4 p0 = csr_pk[e];
            const uint_t v0 = ((const uint_t*)(xh + (size_t)p0.x * 128))[lane];
            const float x0 = bflo(v0), y0 = bfhi(v0);
            const float d0 = __int_as_float(p0.y) * fmaf(sx, x0, sy * y0);
            const int r0 = (e >= b1) + (e >= b2) + (e >= b3) + (e >= b4);
            #pragma unroll
            for (int rr = 0; rr < 5; ++rr) {
                ea[rr] += (r0 == rr ? d0 : 0.0f);
                const float ws0 = (r0 == rr) ? __int_as_float(p0.z) : 0.0f;
                mx[rr] = fmaf(ws0, x0, mx[rr]);
                my[rr] = fmaf(ws0, y0, my[rr]);
            }
        }
        #pragma unroll
        for (int rr = 0; rr < 5; ++rr) {
            __half2 hm = __floats2half2_rn(mx[rr], my[rr]);
            mbuf[(size_t)rr * NL_ + (size_t)n * 64 + lane] =
                *reinterpret_cast<const uint_t*>(&hm);
        }
    }
    __shared__ float sacc[4][10];
    #pragma unroll
    for (int r = 0; r < 5; ++r) {
        float a = na[r], b = ea[r];
        for (int o = 32; o > 0; o >>= 1) {
            a += __shfl_down(a, o, 64);
            b += __shfl_down(b, o, 64);
        }
        if (lane == 0) { sacc[wv][r] = a; sacc[wv][5 + r] = b; }
    }
    __syncthreads();
    if (threadIdx.x < 10) {
        float t = sacc[0][threadIdx.x] + sacc[1][threadIdx.x] +
                  sacc[2][threadIdx.x] + sacc[3][threadIdx.x];
        atomicAdd(&accbuf[k * 16 + threadIdx.x], t);
    }
}

// ---------------------------------------------------------------------------
// scalar: fp32 lane-parallel mirror descent (lanes 0..7 of ONE wave).
// ---------------------------------------------------------------------------
__global__ void scalar_kernel(const float* __restrict__ accbuf, float* __restrict__ ug,
                              float* __restrict__ c_l1, int* __restrict__ act, int k)
{
    if (blockIdx.x != 0 || threadIdx.x >= 8) return;
    const int r = threadIdx.x;
    const int a = act[k];
    float w = (r < 5) ? (accbuf[k * 16 + r] - accbuf[k * 16 + 5 + r]) * (1.0f / 30000.0f)
                      : 0.0f;
    float l1 = fabsf(w);
    for (int o = 4; o > 0; o >>= 1) l1 += __shfl_xor(l1, o, 8);
    if (k == 0 && r == 0) c_l1[0] = l1;
    if (!a) { if (r == 0) act[k + 1] = 0; return; }
    float u = (r < 5) ? ug[r] : 0.0f;
    const float fi = l1 + 3.0f;
    bool mact = true;
    for (int t = 1; t <= 20; ++t) {
        float T = sqrtf(3.2188758248682006f / ((float)t * fi * fi));
        float ta = u * expf(-T * (3.0f * u + w));
        float ssum = ta;
        for (int o = 4; o > 0; o >>= 1) ssum += __shfl_xor(ssum, o, 8);
        float un = ta / ssum;
        float d0 = u - un;
        float dq = d0 * d0;
        for (int o = 4; o > 0; o >>= 1) dq += __shfl_xor(dq, o, 8);
        if (mact) u = un;
        mact = mact && (sqrtf(dq) >= 1e-3f);
    }
    if (r < 5) ug[r] = u;
    if (r == 0) act[k + 1] = (l1 / c_l1[0] >= 0.3f) ? 1 : 0;
}

// ---------------------------------------------------------------------------
// apply: x = x/21 + (20/21)*sum_r u_r m_r — pure streaming with NT hints.
// ---------------------------------------------------------------------------
__global__ __launch_bounds__(256) void apply_kernel(
    float* __restrict__ x, ushort_t* __restrict__ xh_out,
    const uint_t* __restrict__ mbuf, const float* __restrict__ ug,
    const int* __restrict__ act, int k)
{
    if (act[k + 1] == 0) return;
    const int tid = blockIdx.x * 256 + threadIdx.x;
    if (tid >= NL_) return;
    const float u0 = ug[0], u1 = ug[1], u2 = ug[2], u3 = ug[3], u4 = ug[4];

    uint_t w0 = __builtin_nontemporal_load(mbuf + (size_t)0 * NL_ + tid);
    uint_t w1 = __builtin_nontemporal_load(mbuf + (size_t)1 * NL_ + tid);
    uint_t w2 = __builtin_nontemporal_load(mbuf + (size_t)2 * NL_ + tid);
    uint_t w3 = __builtin_nontemporal_load(mbuf + (size_t)3 * NL_ + tid);
    uint_t w4 = __builtin_nontemporal_load(mbuf + (size_t)4 * NL_ + tid);
    const float2 m0 = __half22float2(*reinterpret_cast<const __half2*>(&w0));
    const float2 m1 = __half22float2(*reinterpret_cast<const __half2*>(&w1));
    const float2 m2 = __half22float2(*reinterpret_cast<const __half2*>(&w2));
    const float2 m3 = __half22float2(*reinterpret_cast<const __half2*>(&w3));
    const float2 m4 = __half22float2(*reinterpret_cast<const __half2*>(&w4));

    const float sm_x = u0 * m0.x + u1 * m1.x + u2 * m2.x + u3 * m3.x + u4 * m4.x;
    const float sm_y = u0 * m0.y + u1 * m1.y + u2 * m2.y + u3 * m3.y + u4 * m4.y;

    const float ci = 1.0f / 21.0f, cb = 20.0f / 21.0f;
    f32x2* xp = (f32x2*)x;
    const f32x2 xs = __builtin_nontemporal_load(xp + tid);
    const float nx_ = fmaf(cb, sm_x, xs[0] * ci);
    const float ny_ = fmaf(cb, sm_y, xs[1] * ci);
    f32x2 xn; xn[0] = nx_; xn[1] = ny_;
    __builtin_nontemporal_store(xn, xp + tid);
    ((uint_t*)xh_out)[tid] = ((uint_t)f2bf(ny_) << 16) | (uint_t)f2bf(nx_);
}

// ---------------------------------------------------------------------------
// epilogue: logits = x@Wout + bout ; write logits, x, u
// ---------------------------------------------------------------------------
__global__ __launch_bounds__(256) void final_kernel(const float* __restrict__ x,
                                                    const float* __restrict__ Wout,
                                                    const float* __restrict__ bout,
                                                    const float* __restrict__ ug,
                                                    float* __restrict__ out)
{
    const int nl = threadIdx.x >> 7;
    const int n = blockIdx.x * 2 + nl;
    const int j = threadIdx.x & 127;
    const int lane = threadIdx.x & 63;
    const int wv = threadIdx.x >> 6;
    float xv = x[(size_t)n * 128 + j];
    out[(size_t)NC_ + (size_t)n * 128 + j] = xv;
    float p[8];
    #pragma unroll
    for (int c = 0; c < 8; ++c) p[c] = xv * Wout[j * 8 + c];
    #pragma unroll
    for (int c = 0; c < 8; ++c)
        for (int o = 32; o > 0; o >>= 1) p[c] += __shfl_down(p[c], o, 64);
    __shared__ float sp[4][8];
    if (lane == 0) {
        #pragma unroll
        for (int c = 0; c < 8; ++c) sp[wv][c] = p[c];
    }
    __syncthreads();
    if (j < 8) {
        int c = j;
        out[(size_t)n * 8 + c] = bout[c] + sp[2 * nl][c] + sp[2 * nl + 1][c];
    }
    if (blockIdx.x == 0 && threadIdx.x < 5)
        out[(size_t)NC_ + (size_t)NX_ + threadIdx.x] = ug[threadIdx.x];
}

// ---------------------------------------------------------------------------
extern "C" void kernel_launch(void* const* d_in, const int* in_sizes, int n_in,
                              void* d_out, int out_size, void* d_ws, size_t ws_size,
                              hipStream_t stream)
{
    const float* feat0 = (const float*)d_in[0];
    const float* feat1 = (const float*)d_in[1];
    const float* W0   = (const float*)d_in[2];
    const float* b0   = (const float*)d_in[3];
    const float* W1   = (const float*)d_in[4];
    const float* b1   = (const float*)d_in[5];
    const float* Wm1  = (const float*)d_in[6];
    const float* bm1  = (const float*)d_in[7];
    const float* Wm2  = (const float*)d_in[8];
    const float* bm2  = (const float*)d_in[9];
    const float* Wout = (const float*)d_in[10];
    const float* bout = (const float*)d_in[11];
    const int* src = (const int*)d_in[12];
    const int* dst = (const int*)d_in[13];
    const int* rel = (const int*)d_in[14];
    float* out = (float*)d_out;

    char* p = (char*)d_ws;
    auto alloc = [&](size_t bytes) { char* q = p; p += (bytes + 255) & ~(size_t)255; return q; };
    float*    xbuf      = (float*)   alloc((size_t)NX_ * 4);
    ushort_t* xh0       = (ushort_t*)alloc((size_t)NX_ * 2);
    ushort_t* xh1       = (ushort_t*)alloc((size_t)NX_ * 2);
    uint_t*   mbuf      = (uint_t*)  alloc((size_t)R_ * NL_ * 4);   // 38.4 MB fp16 msgs
    ushort_t* fb0       = (ushort_t*)alloc((size_t)N0_ * 256 * 2);
    ushort_t* fb1       = (ushort_t*)alloc((size_t)(N_TOT - N0_) * 128 * 2);
    ushort_t* wt0       = (ushort_t*)alloc((size_t)128 * 256 * 2);
    ushort_t* wt1       = (ushort_t*)alloc((size_t)128 * 128 * 2);
    ushort_t* wtm1      = (ushort_t*)alloc((size_t)128 * 128 * 2);
    ushort_t* wtm2      = (ushort_t*)alloc((size_t)128 * 128 * 2);
    int*      deg_i     = (int*)     alloc((size_t)RN * 4);
    int*      rp        = (int*)     alloc(((size_t)RN + 1) * 4);
    int*      fill      = (int*)     alloc((size_t)RN * 4);
    int*      bsum      = (int*)     alloc((size_t)SCAN_NB * 4);
    int*      boff      = (int*)     alloc(256 * 4);
    int4*     csr_pk    = (int4*)    alloc((size_t)E_ * 16);
    float*    accbuf    = (float*)   alloc(128 * 4);
    float*    ug        = (float*)   alloc(64);
    float*    c_l1      = (float*)   alloc(64);
    int*      act       = (int*)     alloc(64);

    hipMemsetAsync(deg_i, 0, (size_t)RN * 4, stream);
    hipMemsetAsync(fill, 0, (size_t)RN * 4, stream);
    hipMemsetAsync(accbuf, 0, 128 * 4, stream);
    init_kernel<<<1, 64, 0, stream>>>(ug, act);

    // bf16 pre-conversion
    cvtfeat_kernel<<<(N0_ * 256 / 4 + 255) / 256, 256, 0, stream>>>(feat0, fb0, N0_ * 256);
    cvtfeat_kernel<<<((N_TOT - N0_) * 128 / 4 + 255) / 256, 256, 0, stream>>>(
        feat1, fb1, (N_TOT - N0_) * 128);
    cvtw_kernel<<<(128 * 256 + 255) / 256, 256, 0, stream>>>(W0, wt0, 256);
    cvtw_kernel<<<(128 * 128 + 255) / 256, 256, 0, stream>>>(W1, wt1, 128);
    cvtw_kernel<<<(128 * 128 + 255) / 256, 256, 0, stream>>>(Wm1, wtm1, 128);
    cvtw_kernel<<<(128 * 128 + 255) / 256, 256, 0, stream>>>(Wm2, wtm2, 128);

    mlp_mfma_kernel<<<(N_TOT + 31) / 32, 256, 0, stream>>>(
        fb0, fb1, wt0, wt1, wtm1, wtm2, b0, b1, bm1, bm2, xbuf, xh0);

    deg_kernel<<<(E_ + 255) / 256, 256, 0, stream>>>(src, rel, deg_i);
    scan1_kernel<<<SCAN_NB, 256, 0, stream>>>(deg_i, rp, bsum);
    scan2_kernel<<<1, 256, 0, stream>>>(bsum, boff, rp);
    scan3_kernel<<<SCAN_NB, 256, 0, stream>>>(rp, boff);
    scatter_kernel<<<(E_ + 255) / 256, 256, 0, stream>>>(src, dst, rel, rp, fill,
                                                         deg_i, csr_pk);

    ushort_t* ha = xh0;
    ushort_t* hb = xh1;
    for (int k = 0; k < 8; ++k) {
        gather_kernel<<<2500, 256, 0, stream>>>(ha, rp, csr_pk, act, k, accbuf, mbuf);
        scalar_kernel<<<1, 64, 0, stream>>>(accbuf, ug, c_l1, act, k);
        apply_kernel<<<(NL_ + 255) / 256, 256, 0, stream>>>(xbuf, hb, mbuf, ug, act, k);
        ushort_t* t = ha; ha = hb; hb = t;
    }

    final_kernel<<<N_TOT / 2, 256, 0, stream>>>(xbuf, Wout, bout, ug, out);
}

// Round 13
// 427.157 us; speedup vs baseline: 1.0392x; 1.0210x over previous
//
#include <hip/hip_runtime.h>
#include <hip/hip_fp16.h>
#include <cmath>

typedef unsigned short ushort_t;
typedef unsigned int uint_t;

#define N_TOT 30000
#define N0_   18000
#define R_    5
#define E_    600000
#define RN    (R_ * N_TOT)
#define NC_   (N_TOT * 8)        // logits elements
#define NX_   (N_TOT * 128)      // x elements
#define NL_   (N_TOT * 64)      // node*lane pairs
#define SCAN_NB ((RN + 1023) / 1024)   // 147 blocks of 1024 elements

typedef __attribute__((ext_vector_type(8))) short bf16x8;
typedef __attribute__((ext_vector_type(4))) float f32x4;
typedef __attribute__((ext_vector_type(2))) float f32x2;

__device__ __forceinline__ ushort_t f2bf(float f) {
    uint_t u = __float_as_uint(f);
    uint_t r = (u + 0x7fffu + ((u >> 16) & 1u)) >> 16;   // RTNE
    return (ushort_t)r;
}
__device__ __forceinline__ float bflo(uint_t v) { return __uint_as_float(v << 16); }
__device__ __forceinline__ float bfhi(uint_t v) { return __uint_as_float(v & 0xffff0000u); }

// ---------------------------------------------------------------------------
// init: u = 1/R, act[0]=1, act[1..15]=0
// ---------------------------------------------------------------------------
__global__ void init_kernel(float* ug, int* act) {
    if (threadIdx.x < 16) act[threadIdx.x] = (threadIdx.x == 0) ? 1 : 0;
    if (threadIdx.x < 5) ug[threadIdx.x] = 0.2f;
}

// ---------------------------------------------------------------------------
// bf16 pre-conversion: feats row-major, weights transposed [col][k]
// ---------------------------------------------------------------------------
__global__ __launch_bounds__(256) void cvtfeat_kernel(const float* __restrict__ in,
                                                      ushort_t* __restrict__ out,
                                                      int nelem)
{
    int i = (blockIdx.x * 256 + threadIdx.x) * 4;
    if (i >= nelem) return;
    const float4 v = *(const float4*)(in + i);
    ushort_t o0 = f2bf(v.x), o1 = f2bf(v.y), o2 = f2bf(v.z), o3 = f2bf(v.w);
    uint_t p0 = (uint_t)o0 | ((uint_t)o1 << 16);
    uint_t p1 = (uint_t)o2 | ((uint_t)o3 << 16);
    uint2* op = (uint2*)(out + i);
    *op = make_uint2(p0, p1);
}

__global__ __launch_bounds__(256) void cvtw_kernel(const float* __restrict__ W,
                                                   ushort_t* __restrict__ wt, int K)
{
    int idx = blockIdx.x * 256 + threadIdx.x;   // idx = j*K + k
    if (idx >= 128 * K) return;
    int j = idx / K, k = idx - j * K;
    wt[idx] = f2bf(W[k * 128 + j]);
}

// ---------------------------------------------------------------------------
// MFMA MLP: 32 nodes per 256-thread block (4 waves) — unchanged.
// ---------------------------------------------------------------------------
__global__ __launch_bounds__(256) void mlp_mfma_kernel(
    const ushort_t* __restrict__ fb0, const ushort_t* __restrict__ fb1,
    const ushort_t* __restrict__ wt0, const ushort_t* __restrict__ wt1,
    const ushort_t* __restrict__ wtm1, const ushort_t* __restrict__ wtm2,
    const float* __restrict__ b0, const float* __restrict__ b1,
    const float* __restrict__ bm1, const float* __restrict__ bm2,
    float* __restrict__ xout, ushort_t* __restrict__ xh)
{
    const int t = threadIdx.x;
    const int lane = t & 63;
    const int wv = t >> 6;            // 0..3 -> col block wv*32
    const int lr = lane & 15;         // A-row / B-col within tile
    const int lg = lane >> 4;         // k-group, D row-group
    const int row0 = blockIdx.x * 32;

    __shared__ ushort_t hls[32][136];   // bf16 h   (pad: 272B row stride)
    __shared__ float    tls[32][132];   // fp32 t1/t2 (pad: 528B row stride)
    __shared__ ushort_t zls[32][136];   // bf16 z

    // ---------------- GEMM1: h = feat @ W + b -------------------------------
    #pragma unroll
    for (int mt = 0; mt < 2; ++mt) {
        const int rb = row0 + mt * 16;
        const bool is0 = (rb < N0_);
        const int r = min(rb + lr, N_TOT - 1);
        const ushort_t* __restrict__ fa =
            is0 ? fb0 + (size_t)r * 256 : fb1 + (size_t)(r - N0_) * 128;
        const ushort_t* __restrict__ wt = is0 ? wt0 : wt1;
        const int K = is0 ? 256 : 128;
        const int c0 = wv * 32 + lr;

        f32x4 a0 = {0.f, 0.f, 0.f, 0.f};
        f32x4 a1 = {0.f, 0.f, 0.f, 0.f};
        for (int ks = 0; ks < K; ks += 32) {
            const bf16x8 af = *(const bf16x8*)(fa + ks + lg * 8);
            const bf16x8 wb0 = *(const bf16x8*)(wt + (size_t)c0 * K + ks + lg * 8);
            const bf16x8 wb1 = *(const bf16x8*)(wt + (size_t)(c0 + 16) * K + ks + lg * 8);
            a0 = __builtin_amdgcn_mfma_f32_16x16x32_bf16(af, wb0, a0, 0, 0, 0);
            a1 = __builtin_amdgcn_mfma_f32_16x16x32_bf16(af, wb1, a1, 0, 0, 0);
        }
        const float bb0 = is0 ? b0[c0] : b1[c0];
        const float bb1 = is0 ? b0[c0 + 16] : b1[c0 + 16];
        #pragma unroll
        for (int j = 0; j < 4; ++j) {
            hls[mt * 16 + lg * 4 + j][c0]      = f2bf(a0[j] + bb0);
            hls[mt * 16 + lg * 4 + j][c0 + 16] = f2bf(a1[j] + bb1);
        }
    }
    __syncthreads();

    // ---------------- GEMM2: t1 = h @ Wm1 + bm1 -----------------------------
    {
        const int c0 = wv * 32 + lr;
        f32x4 g00 = {0.f,0.f,0.f,0.f}, g01 = {0.f,0.f,0.f,0.f};
        f32x4 g10 = {0.f,0.f,0.f,0.f}, g11 = {0.f,0.f,0.f,0.f};
        for (int ks = 0; ks < 128; ks += 32) {
            const bf16x8 wb0 = *(const bf16x8*)(wtm1 + (size_t)c0 * 128 + ks + lg * 8);
            const bf16x8 wb1 = *(const bf16x8*)(wtm1 + (size_t)(c0 + 16) * 128 + ks + lg * 8);
            const bf16x8 af0 = *(const bf16x8*)(&hls[lr][ks + lg * 8]);
            const bf16x8 af1 = *(const bf16x8*)(&hls[16 + lr][ks + lg * 8]);
            g00 = __builtin_amdgcn_mfma_f32_16x16x32_bf16(af0, wb0, g00, 0, 0, 0);
            g01 = __builtin_amdgcn_mfma_f32_16x16x32_bf16(af0, wb1, g01, 0, 0, 0);
            g10 = __builtin_amdgcn_mfma_f32_16x16x32_bf16(af1, wb0, g10, 0, 0, 0);
            g11 = __builtin_amdgcn_mfma_f32_16x16x32_bf16(af1, wb1, g11, 0, 0, 0);
        }
        const float bb0 = bm1[c0], bb1 = bm1[c0 + 16];
        #pragma unroll
        for (int j = 0; j < 4; ++j) {
            tls[lg * 4 + j][c0]           = g00[j] + bb0;
            tls[lg * 4 + j][c0 + 16]      = g01[j] + bb1;
            tls[16 + lg * 4 + j][c0]      = g10[j] + bb0;
            tls[16 + lg * 4 + j][c0 + 16] = g11[j] + bb1;
        }
    }
    __syncthreads();

    // ---------------- LN + relu -> z (bf16) ---------------------------------
    {
        const int row = t >> 3, seg = t & 7;
        f32x4 v[4];
        float s = 0.f;
        #pragma unroll
        for (int i = 0; i < 4; ++i) {
            v[i] = *(const f32x4*)(&tls[row][seg * 16 + i * 4]);
            s += v[i][0] + v[i][1] + v[i][2] + v[i][3];
        }
        #pragma unroll
        for (int o = 1; o < 8; o <<= 1) s += __shfl_xor(s, o, 64);
        const float mean = s * (1.0f / 128.0f);
        float q = 0.f;
        #pragma unroll
        for (int i = 0; i < 4; ++i) {
            #pragma unroll
            for (int e = 0; e < 4; ++e) { float d = v[i][e] - mean; q = fmaf(d, d, q); }
        }
        #pragma unroll
        for (int o = 1; o < 8; o <<= 1) q += __shfl_xor(q, o, 64);
        const float inv = 1.0f / sqrtf(q * (1.0f / 128.0f) + 1e-5f);
        uint_t* zp = (uint_t*)&zls[row][0];
        #pragma unroll
        for (int i = 0; i < 4; ++i) {
            ushort_t z0 = f2bf(fmaxf((v[i][0] - mean) * inv, 0.0f));
            ushort_t z1 = f2bf(fmaxf((v[i][1] - mean) * inv, 0.0f));
            ushort_t z2 = f2bf(fmaxf((v[i][2] - mean) * inv, 0.0f));
            ushort_t z3 = f2bf(fmaxf((v[i][3] - mean) * inv, 0.0f));
            zp[(seg * 16 + i * 4) / 2]     = (uint_t)z0 | ((uint_t)z1 << 16);
            zp[(seg * 16 + i * 4) / 2 + 1] = (uint_t)z2 | ((uint_t)z3 << 16);
        }
    }
    __syncthreads();

    // ---------------- GEMM3: t2 = z @ Wm2 + bm2 -----------------------------
    {
        const int c0 = wv * 32 + lr;
        f32x4 g00 = {0.f,0.f,0.f,0.f}, g01 = {0.f,0.f,0.f,0.f};
        f32x4 g10 = {0.f,0.f,0.f,0.f}, g11 = {0.f,0.f,0.f,0.f};
        for (int ks = 0; ks < 128; ks += 32) {
            const bf16x8 wb0 = *(const bf16x8*)(wtm2 + (size_t)c0 * 128 + ks + lg * 8);
            const bf16x8 wb1 = *(const bf16x8*)(wtm2 + (size_t)(c0 + 16) * 128 + ks + lg * 8);
            const bf16x8 af0 = *(const bf16x8*)(&zls[lr][ks + lg * 8]);
            const bf16x8 af1 = *(const bf16x8*)(&zls[16 + lr][ks + lg * 8]);
            g00 = __builtin_amdgcn_mfma_f32_16x16x32_bf16(af0, wb0, g00, 0, 0, 0);
            g01 = __builtin_amdgcn_mfma_f32_16x16x32_bf16(af0, wb1, g01, 0, 0, 0);
            g10 = __builtin_amdgcn_mfma_f32_16x16x32_bf16(af1, wb0, g10, 0, 0, 0);
            g11 = __builtin_amdgcn_mfma_f32_16x16x32_bf16(af1, wb1, g11, 0, 0, 0);
        }
        __syncthreads();   // all zls reads done before tls is overwritten below
        const float bb0 = bm2[c0], bb1 = bm2[c0 + 16];
        #pragma unroll
        for (int j = 0; j < 4; ++j) {
            tls[lg * 4 + j][c0]           = g00[j] + bb0;
            tls[lg * 4 + j][c0 + 16]      = g01[j] + bb1;
            tls[16 + lg * 4 + j][c0]      = g10[j] + bb0;
            tls[16 + lg * 4 + j][c0 + 16] = g11[j] + bb1;
        }
    }
    __syncthreads();

    // ---------------- per-row standardization + store -----------------------
    {
        const int row = t >> 3, seg = t & 7;
        const int n = row0 + row;
        f32x4 v[4];
        float s = 0.f;
        #pragma unroll
        for (int i = 0; i < 4; ++i) {
            v[i] = *(const f32x4*)(&tls[row][seg * 16 + i * 4]);
            s += v[i][0] + v[i][1] + v[i][2] + v[i][3];
        }
        #pragma unroll
        for (int o = 1; o < 8; o <<= 1) s += __shfl_xor(s, o, 64);
        const float mu = s * (1.0f / 128.0f);
        float q = 0.f;
        #pragma unroll
        for (int i = 0; i < 4; ++i) {
            #pragma unroll
            for (int e = 0; e < 4; ++e) { float d = v[i][e] - mu; q = fmaf(d, d, q); }
        }
        #pragma unroll
        for (int o = 1; o < 8; o <<= 1) q += __shfl_xor(q, o, 64);
        const float sd = sqrtf(q * (1.0f / 127.0f));
        const float inv = 1.0f / sd;
        if (n < N_TOT) {
            uint_t* xhp = (uint_t*)xh + (size_t)n * 64 + seg * 8;
            float* xop = xout + (size_t)n * 128 + seg * 16;
            #pragma unroll
            for (int i = 0; i < 4; ++i) {
                float rr[4];
                #pragma unroll
                for (int e = 0; e < 4; ++e) {
                    float r = (v[i][e] - mu) * inv;
                    if (!(fabsf(r) <= 3.402823466e38f)) {
                        r = (r != r) ? 0.0f : ((r > 0.0f) ? 3.402823466e38f : -3.402823466e38f);
                    }
                    rr[e] = r;
                }
                *(float4*)(xop + i * 4) = make_float4(rr[0], rr[1], rr[2], rr[3]);
                xhp[i * 2]     = (uint_t)f2bf(rr[0]) | ((uint_t)f2bf(rr[1]) << 16);
                xhp[i * 2 + 1] = (uint_t)f2bf(rr[2]) | ((uint_t)f2bf(rr[3]) << 16);
            }
        }
    }
}

// ---------------------------------------------------------------------------
// preprocessing — node-major keys: key = src*5 + rel
// ---------------------------------------------------------------------------
__global__ void deg_kernel(const int* __restrict__ src, const int* __restrict__ rel,
                           int* __restrict__ deg_i)
{
    int e = blockIdx.x * 256 + threadIdx.x;
    if (e >= E_) return;
    atomicAdd(&deg_i[src[e] * R_ + rel[e]], 1);
}

// 3-pass parallel exclusive scan over RN elements
__global__ __launch_bounds__(256) void scan1_kernel(const int* __restrict__ cnt,
                                                    int* __restrict__ rp,
                                                    int* __restrict__ bsum)
{
    __shared__ int wsum[4];
    const int t = threadIdx.x, lane = t & 63, w = t >> 6;
    const int i0 = blockIdx.x * 1024 + t * 4;
    const int v0 = (i0 + 0 < RN) ? cnt[i0 + 0] : 0;
    const int v1 = (i0 + 1 < RN) ? cnt[i0 + 1] : 0;
    const int v2 = (i0 + 2 < RN) ? cnt[i0 + 2] : 0;
    const int v3 = (i0 + 3 < RN) ? cnt[i0 + 3] : 0;
    const int s = v0 + v1 + v2 + v3;
    int sc = s;
    #pragma unroll
    for (int o = 1; o < 64; o <<= 1) { int tmp = __shfl_up(sc, o, 64); if (lane >= o) sc += tmp; }
    if (lane == 63) wsum[w] = sc;
    __syncthreads();
    int woff = 0;
    #pragma unroll
    for (int i = 0; i < 3; ++i) if (i < w) woff += wsum[i];
    int run = woff + sc - s;                 // exclusive within block
    if (i0 + 0 < RN) rp[i0 + 0] = run; run += v0;
    if (i0 + 1 < RN) rp[i0 + 1] = run; run += v1;
    if (i0 + 2 < RN) rp[i0 + 2] = run; run += v2;
    if (i0 + 3 < RN) rp[i0 + 3] = run;
    if (t == 255) bsum[blockIdx.x] = woff + sc;   // block total
}

__global__ __launch_bounds__(256) void scan2_kernel(const int* __restrict__ bsum,
                                                    int* __restrict__ boff,
                                                    int* __restrict__ rp)
{
    __shared__ int wsum[4];
    const int t = threadIdx.x, lane = t & 63, w = t >> 6;
    const int v = (t < SCAN_NB) ? bsum[t] : 0;
    int sc = v;
    #pragma unroll
    for (int o = 1; o < 64; o <<= 1) { int tmp = __shfl_up(sc, o, 64); if (lane >= o) sc += tmp; }
    if (lane == 63) wsum[w] = sc;
    __syncthreads();
    int woff = 0;
    #pragma unroll
    for (int i = 0; i < 3; ++i) if (i < w) woff += wsum[i];
    boff[t] = woff + sc - v;                 // exclusive block offset
    if (t == 0) rp[RN] = E_;                 // total degree == E
}

__global__ __launch_bounds__(256) void scan3_kernel(int* __restrict__ rp,
                                                    const int* __restrict__ boff)
{
    const int off = boff[blockIdx.x];
    if (off == 0) return;
    const int i0 = blockIdx.x * 1024 + threadIdx.x * 4;
    if (i0 + 3 < RN) {
        int4* p = (int4*)(rp + i0);
        int4 q = *p;
        q.x += off; q.y += off; q.z += off; q.w += off;
        *p = q;
    } else {
        for (int i = 0; i < 4; ++i)
            if (i0 + i < RN) rp[i0 + i] += off;
    }
}

// scatter: build packed edge records {dst, edinv, w, 0}; dinv computed inline
__global__ void scatter_kernel(const int* __restrict__ src, const int* __restrict__ dst,
                               const int* __restrict__ rel, const int* __restrict__ rp,
                               int* __restrict__ fill, const int* __restrict__ deg_i,
                               int4* __restrict__ csr_pk)
{
    int e = blockIdx.x * 256 + threadIdx.x;
    if (e >= E_) return;
    int s = src[e], r = rel[e], d = dst[e];
    int key = s * R_ + r;
    int pos = rp[key] + atomicAdd(&fill[key], 1);
    int dg_s = deg_i[key];
    int dg_d = deg_i[d * R_ + r];
    float di_s = (dg_s > 0) ? 1.0f / sqrtf((float)dg_s) : 0.0f;
    float di_d = (dg_d > 0) ? 1.0f / sqrtf((float)dg_d) : 0.0f;
    float edinv = di_s * di_d;
    float w = 1.0f / (float)dg_s;
    csr_pk[pos] = make_int4(d, __float_as_int(edinv), __float_as_int(w), 0);
}

// ---------------------------------------------------------------------------
// FUSED gather: merged edge loop, unroll x4, predicated binning, CACHED
// csr_pk loads, NT mbuf stores (write-allocate avoidance).  Grid 2048
// blocks = 8192 waves = exactly one scheduling round on 256 CUs.
// ---------------------------------------------------------------------------
__global__ __launch_bounds__(256) void gather_kernel(
    const ushort_t* __restrict__ xh, const int* __restrict__ rp,
    const int4* __restrict__ csr_pk,
    const int* __restrict__ act, int k, float* __restrict__ accbuf,
    uint_t* __restrict__ mbuf)
{
    if (act[k] == 0) return;
    const int lane = threadIdx.x & 63;
    const int wv = threadIdx.x >> 6;
    const int wid = blockIdx.x * 4 + wv;
    const int nw = gridDim.x * 4;
    float na[5] = {0, 0, 0, 0, 0};
    float ea[5] = {0, 0, 0, 0, 0};
    for (int n = wid; n < N_TOT; n += nw) {
        const int b0 = __builtin_amdgcn_readfirstlane(rp[n * R_ + 0]);
        const int b1 = __builtin_amdgcn_readfirstlane(rp[n * R_ + 1]);
        const int b2 = __builtin_amdgcn_readfirstlane(rp[n * R_ + 2]);
        const int b3 = __builtin_amdgcn_readfirstlane(rp[n * R_ + 3]);
        const int b4 = __builtin_amdgcn_readfirstlane(rp[n * R_ + 4]);
        const int b5 = __builtin_amdgcn_readfirstlane(rp[n * R_ + 5]);
        const uint_t vs = ((const uint_t*)(xh + (size_t)n * 128))[lane];
        const float sx = bflo(vs), sy = bfhi(vs);
        const float pp = fmaf(sx, sx, sy * sy);
        if (b1 > b0) na[0] += pp;
        if (b2 > b1) na[1] += pp;
        if (b3 > b2) na[2] += pp;
        if (b4 > b3) na[3] += pp;
        if (b5 > b4) na[4] += pp;
        float mx[5] = {0, 0, 0, 0, 0};
        float my[5] = {0, 0, 0, 0, 0};
        int e = b0;
        for (; e + 4 <= b5; e += 4) {
            int4 p0 = csr_pk[e + 0];
            int4 p1 = csr_pk[e + 1];
            int4 p2 = csr_pk[e + 2];
            int4 p3 = csr_pk[e + 3];
            const uint_t v0 = ((const uint_t*)(xh + (size_t)p0.x * 128))[lane];
            const uint_t v1 = ((const uint_t*)(xh + (size_t)p1.x * 128))[lane];
            const uint_t v2 = ((const uint_t*)(xh + (size_t)p2.x * 128))[lane];
            const uint_t v3 = ((const uint_t*)(xh + (size_t)p3.x * 128))[lane];
            const float x0 = bflo(v0), y0 = bfhi(v0);
            const float x1 = bflo(v1), y1 = bfhi(v1);
            const float x2 = bflo(v2), y2 = bfhi(v2);
            const float x3 = bflo(v3), y3 = bfhi(v3);
            const float d0 = __int_as_float(p0.y) * fmaf(sx, x0, sy * y0);
            const float d1 = __int_as_float(p1.y) * fmaf(sx, x1, sy * y1);
            const float d2 = __int_as_float(p2.y) * fmaf(sx, x2, sy * y2);
            const float d3 = __int_as_float(p3.y) * fmaf(sx, x3, sy * y3);
            const int r0 = (e + 0 >= b1) + (e + 0 >= b2) + (e + 0 >= b3) + (e + 0 >= b4);
            const int r1 = (e + 1 >= b1) + (e + 1 >= b2) + (e + 1 >= b3) + (e + 1 >= b4);
            const int r2 = (e + 2 >= b1) + (e + 2 >= b2) + (e + 2 >= b3) + (e + 2 >= b4);
            const int r3 = (e + 3 >= b1) + (e + 3 >= b2) + (e + 3 >= b3) + (e + 3 >= b4);
            #pragma unroll
            for (int rr = 0; rr < 5; ++rr) {
                ea[rr] += (r0 == rr ? d0 : 0.0f) + (r1 == rr ? d1 : 0.0f) +
                          (r2 == rr ? d2 : 0.0f) + (r3 == rr ? d3 : 0.0f);
                const float ws0 = (r0 == rr) ? __int_as_float(p0.z) : 0.0f;
                const float ws1 = (r1 == rr) ? __int_as_float(p1.z) : 0.0f;
                const float ws2 = (r2 == rr) ? __int_as_float(p2.z) : 0.0f;
                const float ws3 = (r3 == rr) ? __int_as_float(p3.z) : 0.0f;
                mx[rr] = fmaf(ws0, x0, fmaf(ws1, x1, fmaf(ws2, x2, fmaf(ws3, x3, mx[rr]))));
                my[rr] = fmaf(ws0, y0, fmaf(ws1, y1, fmaf(ws2, y2, fmaf(ws3, y3, my[rr]))));
            }
        }
        for (; e < b5; ++e) {
            int4 p0 = csr_pk[e];
            const uint_t v0 = ((const uint_t*)(xh + (size_t)p0.x * 128))[lane];
            const float x0 = bflo(v0), y0 = bfhi(v0);
            const float d0 = __int_as_float(p0.y) * fmaf(sx, x0, sy * y0);
            const int r0 = (e >= b1) + (e >= b2) + (e >= b3) + (e >= b4);
            #pragma unroll
            for (int rr = 0; rr < 5; ++rr) {
                ea[rr] += (r0 == rr ? d0 : 0.0f);
                const float ws0 = (r0 == rr) ? __int_as_float(p0.z) : 0.0f;
                mx[rr] = fmaf(ws0, x0, mx[rr]);
                my[rr] = fmaf(ws0, y0, my[rr]);
            }
        }
        #pragma unroll
        for (int rr = 0; rr < 5; ++rr) {
            __half2 hm = __floats2half2_rn(mx[rr], my[rr]);
            __builtin_nontemporal_store(*reinterpret_cast<const uint_t*>(&hm),
                mbuf + (size_t)rr * NL_ + (size_t)n * 64 + lane);
        }
    }
    __shared__ float sacc[4][10];
    #pragma unroll
    for (int r = 0; r < 5; ++r) {
        float a = na[r], b = ea[r];
        for (int o = 32; o > 0; o >>= 1) {
            a += __shfl_down(a, o, 64);
            b += __shfl_down(b, o, 64);
        }
        if (lane == 0) { sacc[wv][r] = a; sacc[wv][5 + r] = b; }
    }
    __syncthreads();
    if (threadIdx.x < 10) {
        float t = sacc[0][threadIdx.x] + sacc[1][threadIdx.x] +
                  sacc[2][threadIdx.x] + sacc[3][threadIdx.x];
        atomicAdd(&accbuf[k * 16 + threadIdx.x], t);
    }
}

// ---------------------------------------------------------------------------
// scalar: fp32 lane-parallel mirror descent (lanes 0..7 of ONE wave).
// ---------------------------------------------------------------------------
__global__ void scalar_kernel(const float* __restrict__ accbuf, float* __restrict__ ug,
                              float* __restrict__ c_l1, int* __restrict__ act, int k)
{
    if (blockIdx.x != 0 || threadIdx.x >= 8) return;
    const int r = threadIdx.x;
    const int a = act[k];
    float w = (r < 5) ? (accbuf[k * 16 + r] - accbuf[k * 16 + 5 + r]) * (1.0f / 30000.0f)
                      : 0.0f;
    float l1 = fabsf(w);
    for (int o = 4; o > 0; o >>= 1) l1 += __shfl_xor(l1, o, 8);
    if (k == 0 && r == 0) c_l1[0] = l1;
    if (!a) { if (r == 0) act[k + 1] = 0; return; }
    float u = (r < 5) ? ug[r] : 0.0f;
    const float fi = l1 + 3.0f;
    bool mact = true;
    for (int t = 1; t <= 20; ++t) {
        float T = sqrtf(3.2188758248682006f / ((float)t * fi * fi));
        float ta = u * expf(-T * (3.0f * u + w));
        float ssum = ta;
        for (int o = 4; o > 0; o >>= 1) ssum += __shfl_xor(ssum, o, 8);
        float un = ta / ssum;
        float d0 = u - un;
        float dq = d0 * d0;
        for (int o = 4; o > 0; o >>= 1) dq += __shfl_xor(dq, o, 8);
        if (mact) u = un;
        mact = mact && (sqrtf(dq) >= 1e-3f);
    }
    if (r < 5) ug[r] = u;
    if (r == 0) act[k + 1] = (l1 / c_l1[0] >= 0.3f) ? 1 : 0;
}

// ---------------------------------------------------------------------------
// apply: x = x/21 + (20/21)*sum_r u_r m_r — pure streaming with NT hints.
// ---------------------------------------------------------------------------
__global__ __launch_bounds__(256) void apply_kernel(
    float* __restrict__ x, ushort_t* __restrict__ xh_out,
    const uint_t* __restrict__ mbuf, const float* __restrict__ ug,
    const int* __restrict__ act, int k)
{
    if (act[k + 1] == 0) return;
    const int tid = blockIdx.x * 256 + threadIdx.x;
    if (tid >= NL_) return;
    const float u0 = ug[0], u1 = ug[1], u2 = ug[2], u3 = ug[3], u4 = ug[4];

    uint_t w0 = __builtin_nontemporal_load(mbuf + (size_t)0 * NL_ + tid);
    uint_t w1 = __builtin_nontemporal_load(mbuf + (size_t)1 * NL_ + tid);
    uint_t w2 = __builtin_nontemporal_load(mbuf + (size_t)2 * NL_ + tid);
    uint_t w3 = __builtin_nontemporal_load(mbuf + (size_t)3 * NL_ + tid);
    uint_t w4 = __builtin_nontemporal_load(mbuf + (size_t)4 * NL_ + tid);
    const float2 m0 = __half22float2(*reinterpret_cast<const __half2*>(&w0));
    const float2 m1 = __half22float2(*reinterpret_cast<const __half2*>(&w1));
    const float2 m2 = __half22float2(*reinterpret_cast<const __half2*>(&w2));
    const float2 m3 = __half22float2(*reinterpret_cast<const __half2*>(&w3));
    const float2 m4 = __half22float2(*reinterpret_cast<const __half2*>(&w4));

    const float sm_x = u0 * m0.x + u1 * m1.x + u2 * m2.x + u3 * m3.x + u4 * m4.x;
    const float sm_y = u0 * m0.y + u1 * m1.y + u2 * m2.y + u3 * m3.y + u4 * m4.y;

    const float ci = 1.0f / 21.0f, cb = 20.0f / 21.0f;
    f32x2* xp = (f32x2*)x;
    const f32x2 xs = __builtin_nontemporal_load(xp + tid);
    const float nx_ = fmaf(cb, sm_x, xs[0] * ci);
    const float ny_ = fmaf(cb, sm_y, xs[1] * ci);
    f32x2 xn; xn[0] = nx_; xn[1] = ny_;
    __builtin_nontemporal_store(xn, xp + tid);
    ((uint_t*)xh_out)[tid] = ((uint_t)f2bf(ny_) << 16) | (uint_t)f2bf(nx_);
}

// ---------------------------------------------------------------------------
// epilogue: logits = x@Wout + bout ; write logits, x, u
// ---------------------------------------------------------------------------
__global__ __launch_bounds__(256) void final_kernel(const float* __restrict__ x,
                                                    const float* __restrict__ Wout,
                                                    const float* __restrict__ bout,
                                                    const float* __restrict__ ug,
                                                    float* __restrict__ out)
{
    const int nl = threadIdx.x >> 7;
    const int n = blockIdx.x * 2 + nl;
    const int j = threadIdx.x & 127;
    const int lane = threadIdx.x & 63;
    const int wv = threadIdx.x >> 6;
    float xv = x[(size_t)n * 128 + j];
    out[(size_t)NC_ + (size_t)n * 128 + j] = xv;
    float p[8];
    #pragma unroll
    for (int c = 0; c < 8; ++c) p[c] = xv * Wout[j * 8 + c];
    #pragma unroll
    for (int c = 0; c < 8; ++c)
        for (int o = 32; o > 0; o >>= 1) p[c] += __shfl_down(p[c], o, 64);
    __shared__ float sp[4][8];
    if (lane == 0) {
        #pragma unroll
        for (int c = 0; c < 8; ++c) sp[wv][c] = p[c];
    }
    __syncthreads();
    if (j < 8) {
        int c = j;
        out[(size_t)n * 8 + c] = bout[c] + sp[2 * nl][c] + sp[2 * nl + 1][c];
    }
    if (blockIdx.x == 0 && threadIdx.x < 5)
        out[(size_t)NC_ + (size_t)NX_ + threadIdx.x] = ug[threadIdx.x];
}

// ---------------------------------------------------------------------------
extern "C" void kernel_launch(void* const* d_in, const int* in_sizes, int n_in,
                              void* d_out, int out_size, void* d_ws, size_t ws_size,
                              hipStream_t stream)
{
    const float* feat0 = (const float*)d_in[0];
    const float* feat1 = (const float*)d_in[1];
    const float* W0   = (const float*)d_in[2];
    const float* b0   = (const float*)d_in[3];
    const float* W1   = (const float*)d_in[4];
    const float* b1   = (const float*)d_in[5];
    const float* Wm1  = (const float*)d_in[6];
    const float* bm1  = (const float*)d_in[7];
    const float* Wm2  = (const float*)d_in[8];
    const float* bm2  = (const float*)d_in[9];
    const float* Wout = (const float*)d_in[10];
    const float* bout = (const float*)d_in[11];
    const int* src = (const int*)d_in[12];
    const int* dst = (const int*)d_in[13];
    const int* rel = (const int*)d_in[14];
    float* out = (float*)d_out;

    char* p = (char*)d_ws;
    auto alloc = [&](size_t bytes) { char* q = p; p += (bytes + 255) & ~(size_t)255; return q; };
    float*    xbuf      = (float*)   alloc((size_t)NX_ * 4);
    ushort_t* xh0       = (ushort_t*)alloc((size_t)NX_ * 2);
    ushort_t* xh1       = (ushort_t*)alloc((size_t)NX_ * 2);
    uint_t*   mbuf      = (uint_t*)  alloc((size_t)R_ * NL_ * 4);   // 38.4 MB fp16 msgs
    ushort_t* fb0       = (ushort_t*)alloc((size_t)N0_ * 256 * 2);
    ushort_t* fb1       = (ushort_t*)alloc((size_t)(N_TOT - N0_) * 128 * 2);
    ushort_t* wt0       = (ushort_t*)alloc((size_t)128 * 256 * 2);
    ushort_t* wt1       = (ushort_t*)alloc((size_t)128 * 128 * 2);
    ushort_t* wtm1      = (ushort_t*)alloc((size_t)128 * 128 * 2);
    ushort_t* wtm2      = (ushort_t*)alloc((size_t)128 * 128 * 2);
    int*      deg_i     = (int*)     alloc((size_t)RN * 4);
    int*      rp        = (int*)     alloc(((size_t)RN + 1) * 4);
    int*      fill      = (int*)     alloc((size_t)RN * 4);
    int*      bsum      = (int*)     alloc((size_t)SCAN_NB * 4);
    int*      boff      = (int*)     alloc(256 * 4);
    int4*     csr_pk    = (int4*)    alloc((size_t)E_ * 16);
    float*    accbuf    = (float*)   alloc(128 * 4);
    float*    ug        = (float*)   alloc(64);
    float*    c_l1      = (float*)   alloc(64);
    int*      act       = (int*)     alloc(64);

    hipMemsetAsync(deg_i, 0, (size_t)RN * 4, stream);
    hipMemsetAsync(fill, 0, (size_t)RN * 4, stream);
    hipMemsetAsync(accbuf, 0, 128 * 4, stream);
    init_kernel<<<1, 64, 0, stream>>>(ug, act);

    // bf16 pre-conversion
    cvtfeat_kernel<<<(N0_ * 256 / 4 + 255) / 256, 256, 0, stream>>>(feat0, fb0, N0_ * 256);
    cvtfeat_kernel<<<((N_TOT - N0_) * 128 / 4 + 255) / 256, 256, 0, stream>>>(
        feat1, fb1, (N_TOT - N0_) * 128);
    cvtw_kernel<<<(128 * 256 + 255) / 256, 256, 0, stream>>>(W0, wt0, 256);
    cvtw_kernel<<<(128 * 128 + 255) / 256, 256, 0, stream>>>(W1, wt1, 128);
    cvtw_kernel<<<(128 * 128 + 255) / 256, 256, 0, stream>>>(Wm1, wtm1, 128);
    cvtw_kernel<<<(128 * 128 + 255) / 256, 256, 0, stream>>>(Wm2, wtm2, 128);

    mlp_mfma_kernel<<<(N_TOT + 31) / 32, 256, 0, stream>>>(
        fb0, fb1, wt0, wt1, wtm1, wtm2, b0, b1, bm1, bm2, xbuf, xh0);

    deg_kernel<<<(E_ + 255) / 256, 256, 0, stream>>>(src, rel, deg_i);
    scan1_kernel<<<SCAN_NB, 256, 0, stream>>>(deg_i, rp, bsum);
    scan2_kernel<<<1, 256, 0, stream>>>(bsum, boff, rp);
    scan3_kernel<<<SCAN_NB, 256, 0, stream>>>(rp, boff);
    scatter_kernel<<<(E_ + 255) / 256, 256, 0, stream>>>(src, dst, rel, rp, fill,
                                                         deg_i, csr_pk);

    ushort_t* ha = xh0;
    ushort_t* hb = xh1;
    for (int k = 0; k < 8; ++k) {
        gather_kernel<<<2048, 256, 0, stream>>>(ha, rp, csr_pk, act, k, accbuf, mbuf);
        scalar_kernel<<<1, 64, 0, stream>>>(accbuf, ug, c_l1, act, k);
        apply_kernel<<<(NL_ + 255) / 256, 256, 0, stream>>>(xbuf, hb, mbuf, ug, act, k);
        ushort_t* t = ha; ha = hb; hb = t;
    }

    final_kernel<<<N_TOT / 2, 256, 0, stream>>>(xbuf, Wout, bout, ug, out);
}